// Round 2
// baseline (792.354 us; speedup 1.0000x reference)
//
#include <hip/hip_runtime.h>
#include <stdint.h>

typedef __attribute__((ext_vector_type(8))) __bf16 bf16x8;
typedef __attribute__((ext_vector_type(4))) float f32x4;
typedef __attribute__((ext_vector_type(2))) float f32x2;
typedef __attribute__((ext_vector_type(4))) unsigned uint4v;
typedef __attribute__((ext_vector_type(2))) unsigned uint2v;

union U4 { uint4v u; bf16x8 b; };

// ---- d_ws layout (bytes) ----
#define WS_WDEV_H 0
#define WS_WDEV_L 4096
#define WS_W1_H   8192
#define WS_W1_L   16384
#define WS_W2_H   24576
#define WS_W2_L   32768
#define WS_W3_H   40960
#define WS_W3_L   49152
#define WS_WA_H   57344
#define WS_WA_L   73728
#define WS_WBT    90112
#define WS_WCT    122880
// total 155648 bytes

__device__ __forceinline__ unsigned short f2bf(float f){
  union { float f; unsigned u; } v; v.f = f;
  unsigned r = v.u + 0x7fffu + ((v.u >> 16) & 1u);
  return (unsigned short)(r >> 16);
}
__device__ __forceinline__ float bf2f(unsigned short h){
  union { unsigned u; float f; } v; v.u = ((unsigned)h) << 16; return v.f;
}
__device__ __forceinline__ void split2(float x, unsigned short& hi, unsigned short& lo){
  hi = f2bf(x);
  lo = f2bf(x - bf2f(hi));   // exact residual (cancellation is exact in fp32)
}
__device__ __forceinline__ f32x4 mfma16(const U4& a, const U4& b, f32x4 c){
  return __builtin_amdgcn_mfma_f32_16x16x32_bf16(a.b, b.b, c, 0, 0, 0);
}

// ------------------------------------------------------------------
// prep kernel: split weights into hi/lo bf16 in MFMA B-fragment order,
// plus fp32 transposed copies of Wf1's mean/srv blocks.
// B-frag layout: elem idx = ((ks*NT+nt)*64 + lane)*8 + j,
//   value = W[k][n], k = ks*32 + (lane>>4)*8 + j, n = nt*16 + (lane&15)
// ------------------------------------------------------------------
extern "C" __global__ void prep_weights(const float* __restrict__ Wdev,
                                        const float* __restrict__ W1,
                                        const float* __restrict__ W2,
                                        const float* __restrict__ W3,
                                        const float* __restrict__ Wf1,
                                        char* __restrict__ ws)
{
  unsigned short* WdevH = (unsigned short*)(ws + WS_WDEV_H);
  unsigned short* WdevL = (unsigned short*)(ws + WS_WDEV_L);
  unsigned short* WH[3] = {(unsigned short*)(ws+WS_W1_H),(unsigned short*)(ws+WS_W2_H),(unsigned short*)(ws+WS_W3_H)};
  unsigned short* WL[3] = {(unsigned short*)(ws+WS_W1_L),(unsigned short*)(ws+WS_W2_L),(unsigned short*)(ws+WS_W3_L)};
  unsigned short* WaH = (unsigned short*)(ws + WS_WA_H);
  unsigned short* WaL = (unsigned short*)(ws + WS_WA_L);
  float* WbT = (float*)(ws + WS_WBT);
  float* WcT = (float*)(ws + WS_WCT);
  const int total = 2048 + 3*4096 + 8192 + 2*8192;
  for (int idx = blockIdx.x*256 + threadIdx.x; idx < total; idx += gridDim.x*256){
    if (idx < 2048){                       // Wdev (14x64), K padded to 32, NT=4
      int t = idx;
      int frag = t >> 9, within = t & 511, lane = within >> 3, j = within & 7;
      int nt = frag & 3;
      int k = ((lane>>4)<<3) + j;
      int n = (nt<<4) + (lane & 15);
      float v = (k < 14) ? Wdev[k*64 + n] : 0.f;
      unsigned short h,l; split2(v,h,l); WdevH[t]=h; WdevL[t]=l;
    } else if (idx < 2048 + 3*4096){       // W1/W2/W3 (64x64), KS=2, NT=4
      int t = idx - 2048; int Li = t / 4096; int r = t - Li*4096;
      int frag = r >> 9, within = r & 511, lane = within >> 3, j = within & 7;
      int ks = frag >> 2, nt = frag & 3;
      int k = (ks<<5) + ((lane>>4)<<3) + j;
      int n = (nt<<4) + (lane & 15);
      const float* W = (Li==0) ? W1 : ((Li==1) ? W2 : W3);
      float v = W[k*64 + n];
      unsigned short h,l; split2(v,h,l); WH[Li][r]=h; WL[Li][r]=l;
    } else if (idx < 2048 + 3*4096 + 8192){ // Wa = Wf1 rows 0..63 (64x128), KS=2, NT=8
      int r = idx - (2048 + 3*4096);
      int frag = r >> 9, within = r & 511, lane = within >> 3, j = within & 7;
      int ks = frag >> 3, nt = frag & 7;
      int k = (ks<<5) + ((lane>>4)<<3) + j;
      int n = (nt<<4) + (lane & 15);
      float v = Wf1[k*128 + n];
      unsigned short h,l; split2(v,h,l); WaH[r]=h; WaL[r]=l;
    } else {                                // WbT/WcT: [j][k] fp32, j<128,k<64
      int r = idx - (2048 + 3*4096 + 8192);
      int which = r >> 13; int p = r & 8191; int jj = p >> 6; int k = p & 63;
      if (which == 0) WbT[p] = Wf1[(64 + k)*128 + jj];
      else            WcT[p] = Wf1[(128 + k)*128 + jj];
    }
  }
}

// ------------------------------------------------------------------
// fused PGCN critic: one block per batch item, wave w owns rows 16w..16w+15
// ------------------------------------------------------------------
extern "C" __global__ __launch_bounds__(256, 4)
void pgcn_fused(const float* __restrict__ dobs, const float* __restrict__ sobs,
                const float* __restrict__ adj,
                const float* __restrict__ bdev,
                const float* __restrict__ Wsrv, const float* __restrict__ bsrv,
                const float* __restrict__ b1, const float* __restrict__ b2,
                const float* __restrict__ b3,
                const float* __restrict__ bf1, const float* __restrict__ Wf2,
                const float* __restrict__ bf2,
                const char* __restrict__ ws, float* __restrict__ out)
{
  __shared__ __align__(16) short    lds_A[4096];   // 8 KB: adjacency A-frags; head reuses as f32 scratch (2048 f32)
  __shared__ __align__(16) unsigned lds_R1[4096];  // 16 KB: Y-frags hi|lo  /  per-wave pi-swizzled Z'-transpose
  __shared__ __align__(16) float    lds_d[64];     // d^{-1/2}

  const int t = threadIdx.x;
  const int w = t >> 6;
  const int lane = t & 63;
  const int quad = lane >> 4;
  const int c = lane & 15;
  const long item = blockIdx.x;

  // ---------- stage adjacency -> A-frag layout + degrees ----------
  {
    const f32x4* src = (const f32x4*)(adj + item*4096);
    for (int i = 0; i < 4; ++i){
      int s = (w<<2) + i;
      f32x4 v = src[s*64 + lane];        // elems (m = 4s+quad, k = 4c .. 4c+3)
      int m = (s<<2) + quad;
      int k = c << 2;
      float dp = v.x + v.y + v.z + v.w;  // row-sum partial (16 lanes share m)
      dp += __shfl_xor(dp, 1); dp += __shfl_xor(dp, 2);
      dp += __shfl_xor(dp, 4); dp += __shfl_xor(dp, 8);
      if (c == 0) lds_d[m] = 1.0f / sqrtf(fmaxf(dp, 1.0f));
      unsigned short h0=f2bf(v.x), h1=f2bf(v.y), h2=f2bf(v.z), h3=f2bf(v.w); // exact (0/1)
      int idxs = (((m>>4)*2 + (k>>5)) << 9)
               + (((m&15) + (((k&31)>>3) << 4)) << 3) + (k&7);
      *(uint2v*)&lds_A[idxs] = uint2v{ ((unsigned)h1<<16)|h0, ((unsigned)h3<<16)|h2 };
    }
  }

  // ---------- load device_obs rows as A-operand frags (hi/lo) ----------
  unsigned ahi[4] = {0,0,0,0}, alo[4] = {0,0,0,0};
  {
    int m = (w<<4) + c;
    if (quad < 2 && m < 63){
      const float* rp = dobs + item*882 + m*14 + (quad<<3);
      float e[8];
      f32x2 p0 = *(const f32x2*)(rp);
      f32x2 p1 = *(const f32x2*)(rp+2);
      f32x2 p2 = *(const f32x2*)(rp+4);
      e[0]=p0.x; e[1]=p0.y; e[2]=p1.x; e[3]=p1.y; e[4]=p2.x; e[5]=p2.y;
      if (quad == 0){
        f32x2 p3 = *(const f32x2*)(rp+6);     // k=6,7 (valid)
        e[6]=p3.x; e[7]=p3.y;
      } else {
        e[6]=0.f; e[7]=0.f;                   // k=14,15 pad (no OOB read)
      }
      for (int d0 = 0; d0 < 4; ++d0){
        unsigned short hA,lA,hB,lB;
        split2(e[2*d0], hA, lA);
        split2(e[2*d0+1], hB, lB);
        ahi[d0] = ((unsigned)hB<<16)|hA;
        alo[d0] = ((unsigned)lB<<16)|lA;
      }
    }
  }
  __syncthreads();   // [S] A-frags + d ready

  f32x4 d4v = *(const f32x4*)&lds_d[(w<<4) + (quad<<2)];
  const float dd[4] = {d4v.x, d4v.y, d4v.z, d4v.w};

  // geometry for C-layout -> B-frag (Y) writes
  const int laneCy = c + ((w&1)<<5) + ((quad>>1)<<4);
  const int j0 = (quad&1)<<2;
  const int kspY = w>>1;
  unsigned short* Yhi = (unsigned short*)lds_R1;
  unsigned short* Ylo = ((unsigned short*)lds_R1) + 4096;

  float hcur[4][4];

  // ---------- embed: x = relu(dobs@Wdev + bdev); row63 = server; write Y1 = d*x ----------
  {
    U4 a_h, a_l;
    a_h.u = uint4v{ahi[0],ahi[1],ahi[2],ahi[3]};
    a_l.u = uint4v{alo[0],alo[1],alo[2],alo[3]};
    const uint4v* WdH = (const uint4v*)(ws + WS_WDEV_H);
    const uint4v* WdL = (const uint4v*)(ws + WS_WDEV_L);
    float srvv4[4];
    if (w == 3 && quad == 3){
      float s0 = sobs[item*3+0], s1v = sobs[item*3+1], s2v = sobs[item*3+2];
      for (int nt = 0; nt < 4; ++nt){
        int col = c + (nt<<4);
        float v = s0*Wsrv[col] + s1v*Wsrv[64+col] + s2v*Wsrv[128+col] + bsrv[col];
        srvv4[nt] = fmaxf(v, 0.f);
      }
    }
    for (int nt = 0; nt < 4; ++nt){
      U4 wh, wl;
      wh.u = WdH[(nt<<6) + lane];
      wl.u = WdL[(nt<<6) + lane];
      f32x4 g = {0.f,0.f,0.f,0.f};
      g = mfma16(a_h, wh, g);
      g = mfma16(a_h, wl, g);
      g = mfma16(a_l, wh, g);
      float bb = bdev[c + (nt<<4)];
      float y[4];
      for (int r = 0; r < 4; ++r) y[r] = fmaxf(g[r] + bb, 0.f);
      if (w == 3 && quad == 3) y[3] = srvv4[nt];    // row 63 = server embedding
      for (int r = 0; r < 4; ++r) y[r] *= dd[r];    // pre-scale by d^{-1/2}
      unsigned short yh[4], yl[4];
      for (int r = 0; r < 4; ++r) split2(y[r], yh[r], yl[r]);
      int base = ((((kspY<<2) + nt) << 6) + laneCy)*8 + j0;
      *(uint2v*)&Yhi[base] = uint2v{ ((unsigned)yh[1]<<16)|yh[0], ((unsigned)yh[3]<<16)|yh[2] };
      *(uint2v*)&Ylo[base] = uint2v{ ((unsigned)yl[1]<<16)|yl[0], ((unsigned)yl[3]<<16)|yl[2] };
    }
  }
  __syncthreads();   // Y1 ready

  // ---------- 3 GCN layers ----------
  const uint4v* WH_tab[3] = {(const uint4v*)(ws+WS_W1_H),(const uint4v*)(ws+WS_W2_H),(const uint4v*)(ws+WS_W3_H)};
  const uint4v* WL_tab[3] = {(const uint4v*)(ws+WS_W1_L),(const uint4v*)(ws+WS_W2_L),(const uint4v*)(ws+WS_W3_L)};
  const float* bias_tab[3] = {b1, b2, b3};

  unsigned* zbuf = lds_R1 + (w<<10);                 // per-wave 4 KB transpose slice
  const int piL = (lane>>2) | ((lane&3)<<4);         // bit-rotate swizzle
  const int s0L = (piL>>2) & 1;

  for (int L = 0; L < 3; ++L){
    // step 1: Z = A @ Y   (A binary exact; Y split hi+lo -> 2 passes)
    U4 af0, af1;
    af0.u = ((const uint4v*)lds_A)[((w<<1)+0)*64 + lane];
    af1.u = ((const uint4v*)lds_A)[((w<<1)+1)*64 + lane];
    const uint4v* Yhi4 = (const uint4v*)lds_R1;
    const uint4v* Ylo4 = ((const uint4v*)lds_R1) + 512;
    f32x4 zacc[4];
    for (int nt = 0; nt < 4; ++nt){
      f32x4 g = {0.f,0.f,0.f,0.f};
      U4 yh, yl;
      yh.u = Yhi4[(0*4+nt)*64 + lane]; yl.u = Ylo4[(0*4+nt)*64 + lane];
      g = mfma16(af0, yh, g); g = mfma16(af0, yl, g);
      yh.u = Yhi4[(1*4+nt)*64 + lane]; yl.u = Ylo4[(1*4+nt)*64 + lane];
      g = mfma16(af1, yh, g); g = mfma16(af1, yl, g);
      zacc[nt] = g;
    }
    __syncthreads();  // [B2] all Y reads done; region1 reusable

    // step 2+3: Z' = d*Z, transpose C-layout -> A-frag via pi-swizzled slice
    for (int nt = 0; nt < 4; ++nt){
      int ks = nt >> 1;
      int lcBase = (quad<<2) + ((((nt&1)<<1) + (c>>3)) << 4);
      int e = c & 7;
      for (int r = 0; r < 4; ++r){
        float z = zacc[nt][r] * dd[r];
        unsigned short hz, lz; split2(z, hz, lz);
        int lane_c = lcBase + r;
        int pi = (lane_c>>2) | ((lane_c&3)<<4);
        int sel = ((e>>2) ^ (pi>>2)) & 1;
        zbuf[(ks<<9) + (pi<<3) + (sel<<2) + (e&3)] = ((unsigned)lz<<16) | hz;
      }
    }
    __syncthreads();  // [B2b] transpose writes visible (conservative)
    U4 zh[2], zl[2];
    for (int ks = 0; ks < 2; ++ks){
      uint4v qa = *(const uint4v*)&zbuf[(ks<<9) + (piL<<3) + (s0L<<2)];
      uint4v qb = *(const uint4v*)&zbuf[(ks<<9) + (piL<<3) + ((1-s0L)<<2)];
      zh[ks].u = uint4v{ (qa.y<<16)|(qa.x&0xffffu), (qa.w<<16)|(qa.z&0xffffu),
                         (qb.y<<16)|(qb.x&0xffffu), (qb.w<<16)|(qb.z&0xffffu) };
      zl[ks].u = uint4v{ (qa.y&0xffff0000u)|(qa.x>>16), (qa.w&0xffff0000u)|(qa.z>>16),
                         (qb.y&0xffff0000u)|(qb.x>>16), (qb.w&0xffff0000u)|(qb.z>>16) };
    }

    // step 4+5: G = Z' @ W (3-pass split), h = relu(G + b)
    const uint4v* WHp = WH_tab[L];
    const uint4v* WLp = WL_tab[L];
    const float* bp = bias_tab[L];
    for (int nt = 0; nt < 4; ++nt){
      f32x4 g = {0.f,0.f,0.f,0.f};
      for (int ks = 0; ks < 2; ++ks){
        U4 wh, wl;
        wh.u = WHp[((ks<<2)+nt)*64 + lane];
        wl.u = WLp[((ks<<2)+nt)*64 + lane];
        g = mfma16(zh[ks], wh, g);
        g = mfma16(zh[ks], wl, g);
        g = mfma16(zl[ks], wh, g);
      }
      float bb = bp[c + (nt<<4)];
      for (int r = 0; r < 4; ++r) hcur[nt][r] = fmaxf(g[r] + bb, 0.f);
    }
    __syncthreads();  // [B3] all Z' reads done; region1 reusable

    if (L < 2){
      // step 6: write next Y = d * h
      for (int nt = 0; nt < 4; ++nt){
        float y[4];
        for (int r = 0; r < 4; ++r) y[r] = hcur[nt][r] * dd[r];
        unsigned short yh[4], yl[4];
        for (int r = 0; r < 4; ++r) split2(y[r], yh[r], yl[r]);
        int base = ((((kspY<<2) + nt) << 6) + laneCy)*8 + j0;
        *(uint2v*)&Yhi[base] = uint2v{ ((unsigned)yh[1]<<16)|yh[0], ((unsigned)yh[3]<<16)|yh[2] };
        *(uint2v*)&Ylo[base] = uint2v{ ((unsigned)yl[1]<<16)|yl[0], ((unsigned)yl[3]<<16)|yl[2] };
      }
      __syncthreads();  // next layer's Y ready
    }
  }

  // ---------- head ----------
  // lds_A region = 2048 f32: meanpart[1024] | srvhb[64] @1024 | s1b[128] @1088  (disjoint!)
  float* meanpart = (float*)lds_A;           // 1024 f32: group (w*4+quad)*4+nt, col c
  float* srvhb    = ((float*)lds_A) + 1024;  // 64 f32
  float* s1b      = ((float*)lds_A) + 1088;  // 128 f32
  {
    bool isSrvLane = (w == 3) && (quad == 3);
    for (int nt = 0; nt < 4; ++nt){
      float s = hcur[nt][0] + hcur[nt][1] + hcur[nt][2] + hcur[nt][3];
      if (isSrvLane){ s -= hcur[nt][3]; srvhb[c + (nt<<4)] = hcur[nt][3]; }
      meanpart[((((w<<2)+quad)<<2)+nt)*16 + c] = s;
    }
  }
  __syncthreads();  // [Bh1]

  // s1[j] = mean@Wb + srv@Wc + bf1  (fp32 VALU, split across waves & lane-halves)
  {
    int ntr = lane >> 4, cr = lane & 15;
    float meanv = 0.f;
    for (int i = 0; i < 16; ++i) meanv += meanpart[((i<<2)+ntr)*16 + cr];
    meanv *= (1.0f/63.0f);                 // lane 'col' holds mean[col]
    float srvv = srvhb[lane];
    int jj = (w<<5) + (lane & 31);
    int half = lane >> 5;
    const float* wb = (const float*)(ws + WS_WBT) + jj*64 + (half<<5);
    const float* wc = (const float*)(ws + WS_WCT) + jj*64 + (half<<5);
    float part = 0.f;
    for (int kk = 0; kk < 32; kk += 4){
      f32x4 b4 = *(const f32x4*)(wb + kk);
      f32x4 c4 = *(const f32x4*)(wc + kk);
      int kb = (half<<5) + kk;
      part += __shfl(meanv, kb+0)*b4.x + __shfl(srvv, kb+0)*c4.x;
      part += __shfl(meanv, kb+1)*b4.y + __shfl(srvv, kb+1)*c4.y;
      part += __shfl(meanv, kb+2)*b4.z + __shfl(srvv, kb+2)*c4.z;
      part += __shfl(meanv, kb+3)*b4.w + __shfl(srvv, kb+3)*c4.w;
    }
    part += __shfl_xor(part, 32);
    if (lane < 32) s1b[jj] = part + bf1[jj];
  }

  // transpose h -> A-frags (own zbuf slice; Bh2 below orders it)
  for (int nt = 0; nt < 4; ++nt){
    int ks = nt >> 1;
    int lcBase = (quad<<2) + ((((nt&1)<<1) + (c>>3)) << 4);
    int e = c & 7;
    for (int r = 0; r < 4; ++r){
      unsigned short hz, lz; split2(hcur[nt][r], hz, lz);
      int lane_c = lcBase + r;
      int pi = (lane_c>>2) | ((lane_c&3)<<4);
      int sel = ((e>>2) ^ (pi>>2)) & 1;
      zbuf[(ks<<9) + (pi<<3) + (sel<<2) + (e&3)] = ((unsigned)lz<<16) | hz;
    }
  }
  __syncthreads();  // [Bh2] s1 ready; zbuf writes drained

  U4 hh[2], hl[2];
  for (int ks = 0; ks < 2; ++ks){
    uint4v qa = *(const uint4v*)&zbuf[(ks<<9) + (piL<<3) + (s0L<<2)];
    uint4v qb = *(const uint4v*)&zbuf[(ks<<9) + (piL<<3) + ((1-s0L)<<2)];
    hh[ks].u = uint4v{ (qa.y<<16)|(qa.x&0xffffu), (qa.w<<16)|(qa.z&0xffffu),
                       (qb.y<<16)|(qb.x&0xffffu), (qb.w<<16)|(qb.z&0xffffu) };
    hl[ks].u = uint4v{ (qa.y&0xffff0000u)|(qa.x>>16), (qa.w&0xffff0000u)|(qa.z>>16),
                       (qb.y&0xffff0000u)|(qb.x>>16), (qb.w&0xffff0000u)|(qb.z>>16) };
  }

  // P = h @ Wa (3-pass split), epilogue: out_n = sum_j relu(P+s1)[j]*Wf2[j]
  const uint4v* WaH = (const uint4v*)(ws + WS_WA_H);
  const uint4v* WaL = (const uint4v*)(ws + WS_WA_L);
  float outacc[4] = {0.f,0.f,0.f,0.f};
  for (int nt = 0; nt < 8; ++nt){
    f32x4 g = {0.f,0.f,0.f,0.f};
    for (int ks = 0; ks < 2; ++ks){
      U4 wh, wl;
      wh.u = WaH[((ks<<3)+nt)*64 + lane];
      wl.u = WaL[((ks<<3)+nt)*64 + lane];
      g = mfma16(hh[ks], wh, g);
      g = mfma16(hh[ks], wl, g);
      g = mfma16(hl[ks], wh, g);
    }
    int col = c + (nt<<4);
    float sv = s1b[col];
    float w2 = Wf2[col];
    for (int r = 0; r < 4; ++r){
      float zz = fmaxf(g[r] + sv, 0.f);
      outacc[r] += zz * w2;
    }
  }
  {
    float bb = bf2[0];
    for (int r = 0; r < 4; ++r){
      float v = outacc[r];
      v += __shfl_xor(v, 1); v += __shfl_xor(v, 2);
      v += __shfl_xor(v, 4); v += __shfl_xor(v, 8);
      if (c == 0){
        int row = (w<<4) + (quad<<2) + r;
        if (row < 63) out[item*63 + row] = v + bb;
      }
    }
  }
}

extern "C" void kernel_launch(void* const* d_in, const int* in_sizes, int n_in,
                              void* d_out, int out_size, void* d_ws, size_t ws_size,
                              hipStream_t stream)
{
  const float* dobs = (const float*)d_in[0];
  const float* sobs = (const float*)d_in[1];
  const float* adj  = (const float*)d_in[2];
  const float* Wdev = (const float*)d_in[3];
  const float* bdev = (const float*)d_in[4];
  const float* Wsrv = (const float*)d_in[5];
  const float* bsrv = (const float*)d_in[6];
  const float* W1   = (const float*)d_in[7];
  const float* b1   = (const float*)d_in[8];
  const float* W2   = (const float*)d_in[9];
  const float* b2   = (const float*)d_in[10];
  const float* W3   = (const float*)d_in[11];
  const float* b3   = (const float*)d_in[12];
  const float* Wf1  = (const float*)d_in[13];
  const float* bf1  = (const float*)d_in[14];
  const float* Wf2  = (const float*)d_in[15];
  const float* bf2  = (const float*)d_in[16];
  float* out = (float*)d_out;
  char* ws = (char*)d_ws;
  int nb = in_sizes[1] / 3;   // batch size (server_obs is B x 3)

  prep_weights<<<dim3(160), dim3(256), 0, stream>>>(Wdev, W1, W2, W3, Wf1, ws);
  pgcn_fused<<<dim3(nb), dim3(256), 0, stream>>>(dobs, sobs, adj, bdev, Wsrv, bsrv,
                                                 b1, b2, b3, bf1, Wf2, bf2, ws, out);
}

// Round 3
// 766.124 us; speedup vs baseline: 1.0342x; 1.0342x over previous
//
#include <hip/hip_runtime.h>
#include <stdint.h>

typedef __attribute__((ext_vector_type(8))) __bf16 bf16x8;
typedef __attribute__((ext_vector_type(4))) float f32x4;
typedef __attribute__((ext_vector_type(2))) float f32x2;
typedef __attribute__((ext_vector_type(4))) unsigned uint4v;
typedef __attribute__((ext_vector_type(2))) unsigned uint2v;

union U4 { uint4v u; bf16x8 b; };

// ---- d_ws layout (bytes) ----
#define WS_WDEV_H 0
#define WS_WDEV_L 4096
#define WS_W1_H   8192
#define WS_W1_L   16384
#define WS_W2_H   24576
#define WS_W2_L   32768
#define WS_W3_H   40960
#define WS_W3_L   49152
#define WS_WA_H   57344
#define WS_WA_L   73728
#define WS_WBT    90112
#define WS_WCT    122880
// total 155648 bytes

__device__ __forceinline__ unsigned short f2bf(float f){
  union { float f; unsigned u; } v; v.f = f;
  unsigned r = v.u + 0x7fffu + ((v.u >> 16) & 1u);
  return (unsigned short)(r >> 16);
}
__device__ __forceinline__ float bf2f(unsigned short h){
  union { unsigned u; float f; } v; v.u = ((unsigned)h) << 16; return v.f;
}
__device__ __forceinline__ void split2(float x, unsigned short& hi, unsigned short& lo){
  hi = f2bf(x);
  lo = f2bf(x - bf2f(hi));   // exact residual (cancellation is exact in fp32)
}
__device__ __forceinline__ f32x4 mfma16(const U4& a, const U4& b, f32x4 c){
  return __builtin_amdgcn_mfma_f32_16x16x32_bf16(a.b, b.b, c, 0, 0, 0);
}

// ---- fast RN-bf16 split/pack helpers (bit-identical to split2, fewer VALU ops) ----
__device__ __forceinline__ unsigned rnu(unsigned u){
  return u + 0x7fffu + ((u >> 16) & 1u);   // RN-bf16 rounding in integer domain
}
// hi2 = (bf16(x1)<<16)|bf16(x0), lo2 = same for residuals (RN both)
__device__ __forceinline__ void split_pair(float x0, float x1, unsigned& hi2, unsigned& lo2){
  unsigned u0 = __float_as_uint(x0), u1 = __float_as_uint(x1);
  unsigned r0 = rnu(u0), r1 = rnu(u1);
  float l0 = x0 - __uint_as_float(r0 & 0xffff0000u);
  float l1 = x1 - __uint_as_float(r1 & 0xffff0000u);
  hi2 = __builtin_amdgcn_perm(r1, r0, 0x07060302u);   // [r1.hi16 | r0.hi16]
  unsigned s0 = rnu(__float_as_uint(l0)), s1 = rnu(__float_as_uint(l1));
  lo2 = __builtin_amdgcn_perm(s1, s0, 0x07060302u);
}
// (lo16<<16)|hi16 for one value (zbuf element format)
__device__ __forceinline__ unsigned pack_hl(float z){
  unsigned r = rnu(__float_as_uint(z));
  float lf = z - __uint_as_float(r & 0xffff0000u);
  unsigned s = rnu(__float_as_uint(lf));
  return __builtin_amdgcn_perm(s, r, 0x07060302u);    // low16=hi(z), high16=lo(z)
}

// ------------------------------------------------------------------
// prep kernel: split weights into hi/lo bf16 in MFMA B-fragment order,
// plus fp32 transposed copies of Wf1's mean/srv blocks.
// B-frag layout: elem idx = ((ks*NT+nt)*64 + lane)*8 + j,
//   value = W[k][n], k = ks*32 + (lane>>4)*8 + j, n = nt*16 + (lane&15)
// ------------------------------------------------------------------
extern "C" __global__ void prep_weights(const float* __restrict__ Wdev,
                                        const float* __restrict__ W1,
                                        const float* __restrict__ W2,
                                        const float* __restrict__ W3,
                                        const float* __restrict__ Wf1,
                                        char* __restrict__ ws)
{
  unsigned short* WdevH = (unsigned short*)(ws + WS_WDEV_H);
  unsigned short* WdevL = (unsigned short*)(ws + WS_WDEV_L);
  unsigned short* WH[3] = {(unsigned short*)(ws+WS_W1_H),(unsigned short*)(ws+WS_W2_H),(unsigned short*)(ws+WS_W3_H)};
  unsigned short* WL[3] = {(unsigned short*)(ws+WS_W1_L),(unsigned short*)(ws+WS_W2_L),(unsigned short*)(ws+WS_W3_L)};
  unsigned short* WaH = (unsigned short*)(ws + WS_WA_H);
  unsigned short* WaL = (unsigned short*)(ws + WS_WA_L);
  float* WbT = (float*)(ws + WS_WBT);
  float* WcT = (float*)(ws + WS_WCT);
  const int total = 2048 + 3*4096 + 8192 + 2*8192;
  for (int idx = blockIdx.x*256 + threadIdx.x; idx < total; idx += gridDim.x*256){
    if (idx < 2048){                       // Wdev (14x64), K padded to 32, NT=4
      int t = idx;
      int frag = t >> 9, within = t & 511, lane = within >> 3, j = within & 7;
      int nt = frag & 3;
      int k = ((lane>>4)<<3) + j;
      int n = (nt<<4) + (lane & 15);
      float v = (k < 14) ? Wdev[k*64 + n] : 0.f;
      unsigned short h,l; split2(v,h,l); WdevH[t]=h; WdevL[t]=l;
    } else if (idx < 2048 + 3*4096){       // W1/W2/W3 (64x64), KS=2, NT=4
      int t = idx - 2048; int Li = t / 4096; int r = t - Li*4096;
      int frag = r >> 9, within = r & 511, lane = within >> 3, j = within & 7;
      int ks = frag >> 2, nt = frag & 3;
      int k = (ks<<5) + ((lane>>4)<<3) + j;
      int n = (nt<<4) + (lane & 15);
      const float* W = (Li==0) ? W1 : ((Li==1) ? W2 : W3);
      float v = W[k*64 + n];
      unsigned short h,l; split2(v,h,l); WH[Li][r]=h; WL[Li][r]=l;
    } else if (idx < 2048 + 3*4096 + 8192){ // Wa = Wf1 rows 0..63 (64x128), KS=2, NT=8
      int r = idx - (2048 + 3*4096);
      int frag = r >> 9, within = r & 511, lane = within >> 3, j = within & 7;
      int ks = frag >> 3, nt = frag & 7;
      int k = (ks<<5) + ((lane>>4)<<3) + j;
      int n = (nt<<4) + (lane & 15);
      float v = Wf1[k*128 + n];
      unsigned short h,l; split2(v,h,l); WaH[r]=h; WaL[r]=l;
    } else {                                // WbT/WcT: [j][k] fp32, j<128,k<64
      int r = idx - (2048 + 3*4096 + 8192);
      int which = r >> 13; int p = r & 8191; int jj = p >> 6; int k = p & 63;
      if (which == 0) WbT[p] = Wf1[(64 + k)*128 + jj];
      else            WcT[p] = Wf1[(128 + k)*128 + jj];
    }
  }
}

// ------------------------------------------------------------------
// fused PGCN critic: one block per batch item, wave w owns rows 16w..16w+15
// LDS 24.6 KB/block -> 6 blocks/CU; launch_bounds(256,6) = 24 waves/CU (75%)
// ------------------------------------------------------------------
extern "C" __global__ __launch_bounds__(256, 6)
void pgcn_fused(const float* __restrict__ dobs, const float* __restrict__ sobs,
                const float* __restrict__ adj,
                const float* __restrict__ bdev,
                const float* __restrict__ Wsrv, const float* __restrict__ bsrv,
                const float* __restrict__ b1, const float* __restrict__ b2,
                const float* __restrict__ b3,
                const float* __restrict__ bf1, const float* __restrict__ Wf2,
                const float* __restrict__ bf2,
                const char* __restrict__ ws, float* __restrict__ out)
{
  __shared__ __align__(16) short    lds_A[4096];   // 8 KB: adjacency A-frags; head reuses as f32 scratch (2048 f32)
  __shared__ __align__(16) unsigned lds_R1[4096];  // 16 KB: Y-frags hi|lo  /  per-wave pi-swizzled Z'-transpose
  __shared__ __align__(16) float    lds_d[64];     // d^{-1/2}

  const int t = threadIdx.x;
  const int w = t >> 6;
  const int lane = t & 63;
  const int quad = lane >> 4;
  const int c = lane & 15;
  const long item = blockIdx.x;

  // ---------- stage adjacency -> A-frag layout + degrees ----------
  {
    const f32x4* src = (const f32x4*)(adj + item*4096);
    for (int i = 0; i < 4; ++i){
      int s = (w<<2) + i;
      f32x4 v = src[s*64 + lane];        // elems (m = 4s+quad, k = 4c .. 4c+3)
      int m = (s<<2) + quad;
      int k = c << 2;
      float dp = v.x + v.y + v.z + v.w;  // row-sum partial (16 lanes share m)
      dp += __shfl_xor(dp, 1); dp += __shfl_xor(dp, 2);
      dp += __shfl_xor(dp, 4); dp += __shfl_xor(dp, 8);
      if (c == 0) lds_d[m] = 1.0f / sqrtf(fmaxf(dp, 1.0f));
      // binary values: truncation to bf16 is exact -> single perm per pair
      unsigned p01 = __builtin_amdgcn_perm(__float_as_uint(v.y), __float_as_uint(v.x), 0x07060302u);
      unsigned p23 = __builtin_amdgcn_perm(__float_as_uint(v.w), __float_as_uint(v.z), 0x07060302u);
      int idxs = (((m>>4)*2 + (k>>5)) << 9)
               + (((m&15) + (((k&31)>>3) << 4)) << 3) + (k&7);
      *(uint2v*)&lds_A[idxs] = uint2v{ p01, p23 };
    }
  }

  // ---------- load device_obs rows as A-operand frags (hi/lo) ----------
  unsigned ahi[4] = {0,0,0,0}, alo[4] = {0,0,0,0};
  {
    int m = (w<<4) + c;
    if (quad < 2 && m < 63){
      const float* rp = dobs + item*882 + m*14 + (quad<<3);
      float e[8];
      f32x2 p0 = *(const f32x2*)(rp);
      f32x2 p1 = *(const f32x2*)(rp+2);
      f32x2 p2 = *(const f32x2*)(rp+4);
      e[0]=p0.x; e[1]=p0.y; e[2]=p1.x; e[3]=p1.y; e[4]=p2.x; e[5]=p2.y;
      if (quad == 0){
        f32x2 p3 = *(const f32x2*)(rp+6);     // k=6,7 (valid)
        e[6]=p3.x; e[7]=p3.y;
      } else {
        e[6]=0.f; e[7]=0.f;                   // k=14,15 pad (no OOB read)
      }
      for (int d0 = 0; d0 < 4; ++d0)
        split_pair(e[2*d0], e[2*d0+1], ahi[d0], alo[d0]);
    }
  }
  __syncthreads();   // [S] A-frags + d ready

  f32x4 d4v = *(const f32x4*)&lds_d[(w<<4) + (quad<<2)];
  const float dd[4] = {d4v.x, d4v.y, d4v.z, d4v.w};

  // geometry for C-layout -> B-frag (Y) writes
  const int laneCy = c + ((w&1)<<5) + ((quad>>1)<<4);
  const int j0 = (quad&1)<<2;
  const int kspY = w>>1;
  unsigned short* Yhi = (unsigned short*)lds_R1;
  unsigned short* Ylo = ((unsigned short*)lds_R1) + 4096;

  float hcur[4][4];

  // ---------- embed: x = relu(dobs@Wdev + bdev); row63 = server; write Y1 = d*x ----------
  {
    U4 a_h, a_l;
    a_h.u = uint4v{ahi[0],ahi[1],ahi[2],ahi[3]};
    a_l.u = uint4v{alo[0],alo[1],alo[2],alo[3]};
    const uint4v* WdH = (const uint4v*)(ws + WS_WDEV_H);
    const uint4v* WdL = (const uint4v*)(ws + WS_WDEV_L);
    float srvv4[4];
    if (w == 3 && quad == 3){
      float s0 = sobs[item*3+0], s1v = sobs[item*3+1], s2v = sobs[item*3+2];
      for (int nt = 0; nt < 4; ++nt){
        int col = c + (nt<<4);
        float v = s0*Wsrv[col] + s1v*Wsrv[64+col] + s2v*Wsrv[128+col] + bsrv[col];
        srvv4[nt] = fmaxf(v, 0.f);
      }
    }
    for (int nt = 0; nt < 4; ++nt){
      U4 wh, wl;
      wh.u = WdH[(nt<<6) + lane];
      wl.u = WdL[(nt<<6) + lane];
      f32x4 g = {0.f,0.f,0.f,0.f};
      g = mfma16(a_h, wh, g);
      g = mfma16(a_h, wl, g);
      g = mfma16(a_l, wh, g);
      float bb = bdev[c + (nt<<4)];
      float y[4];
      for (int r = 0; r < 4; ++r) y[r] = fmaxf(g[r] + bb, 0.f);
      if (w == 3 && quad == 3) y[3] = srvv4[nt];    // row 63 = server embedding
      for (int r = 0; r < 4; ++r) y[r] *= dd[r];    // pre-scale by d^{-1/2}
      unsigned h01, l01, h23, l23;
      split_pair(y[0], y[1], h01, l01);
      split_pair(y[2], y[3], h23, l23);
      int base = ((((kspY<<2) + nt) << 6) + laneCy)*8 + j0;
      *(uint2v*)&Yhi[base] = uint2v{ h01, h23 };
      *(uint2v*)&Ylo[base] = uint2v{ l01, l23 };
    }
  }
  __syncthreads();   // Y1 ready

  // ---------- 3 GCN layers ----------
  const uint4v* WH_tab[3] = {(const uint4v*)(ws+WS_W1_H),(const uint4v*)(ws+WS_W2_H),(const uint4v*)(ws+WS_W3_H)};
  const uint4v* WL_tab[3] = {(const uint4v*)(ws+WS_W1_L),(const uint4v*)(ws+WS_W2_L),(const uint4v*)(ws+WS_W3_L)};
  const float* bias_tab[3] = {b1, b2, b3};

  unsigned* zbuf = lds_R1 + (w<<10);                 // per-wave 4 KB transpose slice
  const int piL = (lane>>2) | ((lane&3)<<4);         // bit-rotate swizzle
  const int s0L = (piL>>2) & 1;

  for (int L = 0; L < 3; ++L){
    // step 1: Z = A @ Y   (A binary exact; Y split hi+lo -> 2 passes)
    U4 af0, af1;
    af0.u = ((const uint4v*)lds_A)[((w<<1)+0)*64 + lane];
    af1.u = ((const uint4v*)lds_A)[((w<<1)+1)*64 + lane];
    const uint4v* Yhi4 = (const uint4v*)lds_R1;
    const uint4v* Ylo4 = ((const uint4v*)lds_R1) + 512;
    f32x4 zacc[4];
    for (int nt = 0; nt < 4; ++nt){
      f32x4 g = {0.f,0.f,0.f,0.f};
      U4 yh, yl;
      yh.u = Yhi4[(0*4+nt)*64 + lane]; yl.u = Ylo4[(0*4+nt)*64 + lane];
      g = mfma16(af0, yh, g); g = mfma16(af0, yl, g);
      yh.u = Yhi4[(1*4+nt)*64 + lane]; yl.u = Ylo4[(1*4+nt)*64 + lane];
      g = mfma16(af1, yh, g); g = mfma16(af1, yl, g);
      zacc[nt] = g;
    }
    __syncthreads();  // [B2] all Y reads done; region1 reusable

    // step 2+3: Z' = d*Z, transpose C-layout -> A-frag via pi-swizzled PER-WAVE slice
    for (int nt = 0; nt < 4; ++nt){
      int ks = nt >> 1;
      int lcBase = (quad<<2) + ((((nt&1)<<1) + (c>>3)) << 4);
      int e = c & 7;
      for (int r = 0; r < 4; ++r){
        unsigned pk = pack_hl(zacc[nt][r] * dd[r]);
        int lane_c = lcBase + r;
        int pi = (lane_c>>2) | ((lane_c&3)<<4);
        int sel = ((e>>2) ^ (pi>>2)) & 1;
        zbuf[(ks<<9) + (pi<<3) + (sel<<2) + (e&3)] = pk;
      }
    }
    __threadfence_block();   // wave-private slice: order writes before reads (no x-wave dep)
    U4 zh[2], zl[2];
    for (int ks = 0; ks < 2; ++ks){
      uint4v qa = *(const uint4v*)&zbuf[(ks<<9) + (piL<<3) + (s0L<<2)];
      uint4v qb = *(const uint4v*)&zbuf[(ks<<9) + (piL<<3) + ((1-s0L)<<2)];
      zh[ks].u = uint4v{ (qa.y<<16)|(qa.x&0xffffu), (qa.w<<16)|(qa.z&0xffffu),
                         (qb.y<<16)|(qb.x&0xffffu), (qb.w<<16)|(qb.z&0xffffu) };
      zl[ks].u = uint4v{ (qa.y&0xffff0000u)|(qa.x>>16), (qa.w&0xffff0000u)|(qa.z>>16),
                         (qb.y&0xffff0000u)|(qb.x>>16), (qb.w&0xffff0000u)|(qb.z>>16) };
    }

    // step 4+5: G = Z' @ W (3-pass split), h = relu(G + b)
    const uint4v* WHp = WH_tab[L];
    const uint4v* WLp = WL_tab[L];
    const float* bp = bias_tab[L];
    for (int nt = 0; nt < 4; ++nt){
      f32x4 g = {0.f,0.f,0.f,0.f};
      for (int ks = 0; ks < 2; ++ks){
        U4 wh, wl;
        wh.u = WHp[((ks<<2)+nt)*64 + lane];
        wl.u = WLp[((ks<<2)+nt)*64 + lane];
        g = mfma16(zh[ks], wh, g);
        g = mfma16(zh[ks], wl, g);
        g = mfma16(zl[ks], wh, g);
      }
      float bb = bp[c + (nt<<4)];
      for (int r = 0; r < 4; ++r) hcur[nt][r] = fmaxf(g[r] + bb, 0.f);
    }
    __syncthreads();  // [B3] all Z' reads done; region1 reusable

    if (L < 2){
      // step 6: write next Y = d * h
      for (int nt = 0; nt < 4; ++nt){
        unsigned h01, l01, h23, l23;
        split_pair(hcur[nt][0]*dd[0], hcur[nt][1]*dd[1], h01, l01);
        split_pair(hcur[nt][2]*dd[2], hcur[nt][3]*dd[3], h23, l23);
        int base = ((((kspY<<2) + nt) << 6) + laneCy)*8 + j0;
        *(uint2v*)&Yhi[base] = uint2v{ h01, h23 };
        *(uint2v*)&Ylo[base] = uint2v{ l01, l23 };
      }
      __syncthreads();  // next layer's Y ready
    }
  }

  // ---------- head ----------
  // lds_A region = 2048 f32: meanpart[1024] | srvhb[64] @1024 | s1b[128] @1088  (disjoint!)
  float* meanpart = (float*)lds_A;           // 1024 f32: group (w*4+quad)*4+nt, col c
  float* srvhb    = ((float*)lds_A) + 1024;  // 64 f32
  float* s1b      = ((float*)lds_A) + 1088;  // 128 f32
  {
    bool isSrvLane = (w == 3) && (quad == 3);
    for (int nt = 0; nt < 4; ++nt){
      float s = hcur[nt][0] + hcur[nt][1] + hcur[nt][2] + hcur[nt][3];
      if (isSrvLane){ s -= hcur[nt][3]; srvhb[c + (nt<<4)] = hcur[nt][3]; }
      meanpart[((((w<<2)+quad)<<2)+nt)*16 + c] = s;
    }
  }
  __syncthreads();  // [Bh1]

  // s1[j] = mean@Wb + srv@Wc + bf1  (fp32 VALU, split across waves & lane-halves)
  {
    int ntr = lane >> 4, cr = lane & 15;
    float meanv = 0.f;
    for (int i = 0; i < 16; ++i) meanv += meanpart[((i<<2)+ntr)*16 + cr];
    meanv *= (1.0f/63.0f);                 // lane 'col' holds mean[col]
    float srvv = srvhb[lane];
    int jj = (w<<5) + (lane & 31);
    int half = lane >> 5;
    const float* wb = (const float*)(ws + WS_WBT) + jj*64 + (half<<5);
    const float* wc = (const float*)(ws + WS_WCT) + jj*64 + (half<<5);
    float part = 0.f;
    for (int kk = 0; kk < 32; kk += 4){
      f32x4 b4 = *(const f32x4*)(wb + kk);
      f32x4 c4 = *(const f32x4*)(wc + kk);
      int kb = (half<<5) + kk;
      part += __shfl(meanv, kb+0)*b4.x + __shfl(srvv, kb+0)*c4.x;
      part += __shfl(meanv, kb+1)*b4.y + __shfl(srvv, kb+1)*c4.y;
      part += __shfl(meanv, kb+2)*b4.z + __shfl(srvv, kb+2)*c4.z;
      part += __shfl(meanv, kb+3)*b4.w + __shfl(srvv, kb+3)*c4.w;
    }
    part += __shfl_xor(part, 32);
    if (lane < 32) s1b[jj] = part + bf1[jj];
  }

  // transpose h -> A-frags (own zbuf slice; Bh2 below orders it)
  for (int nt = 0; nt < 4; ++nt){
    int ks = nt >> 1;
    int lcBase = (quad<<2) + ((((nt&1)<<1) + (c>>3)) << 4);
    int e = c & 7;
    for (int r = 0; r < 4; ++r){
      unsigned pk = pack_hl(hcur[nt][r]);
      int lane_c = lcBase + r;
      int pi = (lane_c>>2) | ((lane_c&3)<<4);
      int sel = ((e>>2) ^ (pi>>2)) & 1;
      zbuf[(ks<<9) + (pi<<3) + (sel<<2) + (e&3)] = pk;
    }
  }
  __syncthreads();  // [Bh2] s1 ready; zbuf writes drained

  U4 hh[2], hl[2];
  for (int ks = 0; ks < 2; ++ks){
    uint4v qa = *(const uint4v*)&zbuf[(ks<<9) + (piL<<3) + (s0L<<2)];
    uint4v qb = *(const uint4v*)&zbuf[(ks<<9) + (piL<<3) + ((1-s0L)<<2)];
    hh[ks].u = uint4v{ (qa.y<<16)|(qa.x&0xffffu), (qa.w<<16)|(qa.z&0xffffu),
                       (qb.y<<16)|(qb.x&0xffffu), (qb.w<<16)|(qb.z&0xffffu) };
    hl[ks].u = uint4v{ (qa.y&0xffff0000u)|(qa.x>>16), (qa.w&0xffff0000u)|(qa.z>>16),
                       (qb.y&0xffff0000u)|(qb.x>>16), (qb.w&0xffff0000u)|(qb.z>>16) };
  }

  // P = h @ Wa (3-pass split), epilogue: out_n = sum_j relu(P+s1)[j]*Wf2[j]
  const uint4v* WaH = (const uint4v*)(ws + WS_WA_H);
  const uint4v* WaL = (const uint4v*)(ws + WS_WA_L);
  float outacc[4] = {0.f,0.f,0.f,0.f};
  for (int nt = 0; nt < 8; ++nt){
    f32x4 g = {0.f,0.f,0.f,0.f};
    for (int ks = 0; ks < 2; ++ks){
      U4 wh, wl;
      wh.u = WaH[((ks<<3)+nt)*64 + lane];
      wl.u = WaL[((ks<<3)+nt)*64 + lane];
      g = mfma16(hh[ks], wh, g);
      g = mfma16(hh[ks], wl, g);
      g = mfma16(hl[ks], wh, g);
    }
    int col = c + (nt<<4);
    float sv = s1b[col];
    float w2 = Wf2[col];
    for (int r = 0; r < 4; ++r){
      float zz = fmaxf(g[r] + sv, 0.f);
      outacc[r] += zz * w2;
    }
  }
  {
    float bb = bf2[0];
    for (int r = 0; r < 4; ++r){
      float v = outacc[r];
      v += __shfl_xor(v, 1); v += __shfl_xor(v, 2);
      v += __shfl_xor(v, 4); v += __shfl_xor(v, 8);
      if (c == 0){
        int row = (w<<4) + (quad<<2) + r;
        if (row < 63) out[item*63 + row] = v + bb;
      }
    }
  }
}

extern "C" void kernel_launch(void* const* d_in, const int* in_sizes, int n_in,
                              void* d_out, int out_size, void* d_ws, size_t ws_size,
                              hipStream_t stream)
{
  const float* dobs = (const float*)d_in[0];
  const float* sobs = (const float*)d_in[1];
  const float* adj  = (const float*)d_in[2];
  const float* Wdev = (const float*)d_in[3];
  const float* bdev = (const float*)d_in[4];
  const float* Wsrv = (const float*)d_in[5];
  const float* bsrv = (const float*)d_in[6];
  const float* W1   = (const float*)d_in[7];
  const float* b1   = (const float*)d_in[8];
  const float* W2   = (const float*)d_in[9];
  const float* b2   = (const float*)d_in[10];
  const float* W3   = (const float*)d_in[11];
  const float* b3   = (const float*)d_in[12];
  const float* Wf1  = (const float*)d_in[13];
  const float* bf1  = (const float*)d_in[14];
  const float* Wf2  = (const float*)d_in[15];
  const float* bf2  = (const float*)d_in[16];
  float* out = (float*)d_out;
  char* ws = (char*)d_ws;
  int nb = in_sizes[1] / 3;   // batch size (server_obs is B x 3)

  prep_weights<<<dim3(160), dim3(256), 0, stream>>>(Wdev, W1, W2, W3, Wf1, ws);
  pgcn_fused<<<dim3(nb), dim3(256), 0, stream>>>(dobs, sobs, adj, bdev, Wsrv, bsrv,
                                                 b1, b2, b3, bf1, Wf2, bf2, ws, out);
}

// Round 4
// 752.695 us; speedup vs baseline: 1.0527x; 1.0178x over previous
//
#include <hip/hip_runtime.h>
#include <stdint.h>

typedef __attribute__((ext_vector_type(8))) __bf16 bf16x8;
typedef __attribute__((ext_vector_type(4))) float f32x4;
typedef __attribute__((ext_vector_type(2))) float f32x2;
typedef __attribute__((ext_vector_type(4))) unsigned uint4v;
typedef __attribute__((ext_vector_type(2))) unsigned uint2v;

union U4 { uint4v u; bf16x8 b; };

// ---- d_ws layout (bytes) ----
#define WS_WDEV_H 0
#define WS_WDEV_L 4096
#define WS_W1_H   8192
#define WS_W1_L   16384
#define WS_W2_H   24576
#define WS_W2_L   32768
#define WS_W3_H   40960
#define WS_W3_L   49152
#define WS_WA_H   57344
#define WS_WA_L   73728
#define WS_WF_H   90112
#define WS_WF_L   122880
// total 155648 bytes (same footprint as R3: WbT/WcT fp32 -> Wfull bf16 hi/lo)

__device__ __forceinline__ unsigned short f2bf(float f){
  union { float f; unsigned u; } v; v.f = f;
  unsigned r = v.u + 0x7fffu + ((v.u >> 16) & 1u);
  return (unsigned short)(r >> 16);
}
__device__ __forceinline__ float bf2f(unsigned short h){
  union { unsigned u; float f; } v; v.u = ((unsigned)h) << 16; return v.f;
}
__device__ __forceinline__ void split2(float x, unsigned short& hi, unsigned short& lo){
  hi = f2bf(x);
  lo = f2bf(x - bf2f(hi));   // exact residual
}
__device__ __forceinline__ f32x4 mfma16(const U4& a, const U4& b, f32x4 c){
  return __builtin_amdgcn_mfma_f32_16x16x32_bf16(a.b, b.b, c, 0, 0, 0);
}

// ---- fast RN-bf16 split/pack helpers ----
__device__ __forceinline__ unsigned rnu(unsigned u){
  return u + 0x7fffu + ((u >> 16) & 1u);
}
__device__ __forceinline__ void split_pair(float x0, float x1, unsigned& hi2, unsigned& lo2){
  unsigned r0 = rnu(__float_as_uint(x0)), r1 = rnu(__float_as_uint(x1));
  float l0 = x0 - __uint_as_float(r0 & 0xffff0000u);
  float l1 = x1 - __uint_as_float(r1 & 0xffff0000u);
  hi2 = __builtin_amdgcn_perm(r1, r0, 0x07060302u);
  unsigned s0 = rnu(__float_as_uint(l0)), s1 = rnu(__float_as_uint(l1));
  lo2 = __builtin_amdgcn_perm(s1, s0, 0x07060302u);
}
__device__ __forceinline__ unsigned pack_hl(float z){
  unsigned r = rnu(__float_as_uint(z));
  float lf = z - __uint_as_float(r & 0xffff0000u);
  unsigned s = rnu(__float_as_uint(lf));
  return __builtin_amdgcn_perm(s, r, 0x07060302u);    // low16=hi(z), high16=lo(z)
}

// ------------------------------------------------------------------
// prep kernel: weights -> hi/lo bf16 MFMA B-fragments.
// B-frag: idx = ((ks*NT+nt)*64 + lane)*8 + j ; k = ks*32+(lane>>4)*8+j, n = nt*16+(lane&15)
// ------------------------------------------------------------------
extern "C" __global__ void prep_weights(const float* __restrict__ Wdev,
                                        const float* __restrict__ W1,
                                        const float* __restrict__ W2,
                                        const float* __restrict__ W3,
                                        const float* __restrict__ Wf1,
                                        char* __restrict__ ws)
{
  unsigned short* WdevH = (unsigned short*)(ws + WS_WDEV_H);
  unsigned short* WdevL = (unsigned short*)(ws + WS_WDEV_L);
  unsigned short* WH[3] = {(unsigned short*)(ws+WS_W1_H),(unsigned short*)(ws+WS_W2_H),(unsigned short*)(ws+WS_W3_H)};
  unsigned short* WL[3] = {(unsigned short*)(ws+WS_W1_L),(unsigned short*)(ws+WS_W2_L),(unsigned short*)(ws+WS_W3_L)};
  unsigned short* WaH = (unsigned short*)(ws + WS_WA_H);
  unsigned short* WaL = (unsigned short*)(ws + WS_WA_L);
  unsigned short* WfH = (unsigned short*)(ws + WS_WF_H);
  unsigned short* WfL = (unsigned short*)(ws + WS_WF_L);
  const int total = 2048 + 3*4096 + 8192 + 16384;
  for (int idx = blockIdx.x*256 + threadIdx.x; idx < total; idx += gridDim.x*256){
    if (idx < 2048){                       // Wdev (14x64), K padded to 32, NT=4
      int tt = idx;
      int frag = tt >> 9, within = tt & 511, lane = within >> 3, j = within & 7;
      int nt = frag & 3;
      int k = ((lane>>4)<<3) + j;
      int n = (nt<<4) + (lane & 15);
      float v = (k < 14) ? Wdev[k*64 + n] : 0.f;
      unsigned short h,l; split2(v,h,l); WdevH[tt]=h; WdevL[tt]=l;
    } else if (idx < 2048 + 3*4096){       // W1/W2/W3 (64x64), KS=2, NT=4
      int tt = idx - 2048; int Li = tt / 4096; int r = tt - Li*4096;
      int frag = r >> 9, within = r & 511, lane = within >> 3, j = within & 7;
      int ks = frag >> 2, nt = frag & 3;
      int k = (ks<<5) + ((lane>>4)<<3) + j;
      int n = (nt<<4) + (lane & 15);
      const float* W = (Li==0) ? W1 : ((Li==1) ? W2 : W3);
      float v = W[k*64 + n];
      unsigned short h,l; split2(v,h,l); WH[Li][r]=h; WL[Li][r]=l;
    } else if (idx < 2048 + 3*4096 + 8192){ // Wa = Wf1 rows 0..63 (64x128), KS=2, NT=8
      int r = idx - (2048 + 3*4096);
      int frag = r >> 9, within = r & 511, lane = within >> 3, j = within & 7;
      int ks = frag >> 3, nt = frag & 7;
      int k = (ks<<5) + ((lane>>4)<<3) + j;
      int n = (nt<<4) + (lane & 15);
      float v = Wf1[k*128 + n];
      unsigned short h,l; split2(v,h,l); WaH[r]=h; WaL[r]=l;
    } else {                                // Wfull = Wf1 rows 64..191 (128x128), KS=4, NT=8
      int r = idx - (2048 + 3*4096 + 8192);
      int frag = r >> 9, within = r & 511, lane = within >> 3, j = within & 7;
      int ks = frag >> 3, nt = frag & 7;
      int k = (ks<<5) + ((lane>>4)<<3) + j;
      int n = (nt<<4) + (lane & 15);
      float v = Wf1[(64 + k)*128 + n];
      unsigned short h,l; split2(v,h,l); WfH[r]=h; WfL[r]=l;
    }
  }
}

// ------------------------------------------------------------------
// fused PGCN critic: one block per batch item, wave w owns rows 16w..16w+15
// LDS ~19.5 KB -> 8 blocks/CU (32 waves/CU, 100% slots)
// ------------------------------------------------------------------
extern "C" __global__ __launch_bounds__(256, 8)
void pgcn_fused(const float* __restrict__ dobs, const float* __restrict__ sobs,
                const float* __restrict__ adj,
                const float* __restrict__ bdev,
                const float* __restrict__ Wsrv, const float* __restrict__ bsrv,
                const float* __restrict__ b1, const float* __restrict__ b2,
                const float* __restrict__ b3,
                const float* __restrict__ bf1, const float* __restrict__ Wf2,
                const float* __restrict__ bf2,
                const char* __restrict__ ws, float* __restrict__ out)
{
  __shared__ __align__(16) unsigned long long lds_Abits[64];  // 512 B adjacency bitmask
  __shared__ __align__(16) float    lds_d[64];                // d^{-1/2}
  __shared__ __align__(16) unsigned lds_R1[4096];             // 16 KB: Y hi|lo B-frags / per-wave zbuf
  __shared__ __align__(16) float    lds_mp[256];              // per-wave col-sum partials
  __shared__ __align__(16) float    lds_srv[64];
  __shared__ __align__(16) float    lds_s1[128];
  __shared__ __align__(16) unsigned short lds_Vh[128];
  __shared__ __align__(16) unsigned short lds_Vl[128];

  const int t = threadIdx.x;
  const int w = t >> 6;
  const int lane = t & 63;
  const int quad = lane >> 4;
  const int c = lane & 15;
  const long item = blockIdx.x;

  // ---------- stage adjacency as bitmask: thread t -> row t>>2, 16-col chunk t&3 ----------
  {
    const f32x4* src = (const f32x4*)(adj + item*4096 + ((t>>2)<<6) + ((t&3)<<4));
    unsigned bits = 0;
    for (int i = 0; i < 4; ++i){
      f32x4 v = src[i];
      unsigned b = (v.x != 0.f) | (((unsigned)(v.y != 0.f))<<1)
                 | (((unsigned)(v.z != 0.f))<<2) | (((unsigned)(v.w != 0.f))<<3);
      bits |= b << (i<<2);
    }
    ((unsigned short*)lds_Abits)[t] = (unsigned short)bits;
  }

  // ---------- load device_obs rows as A-operand frags (hi/lo) ----------
  unsigned ahi[4] = {0,0,0,0}, alo[4] = {0,0,0,0};
  {
    int m = (w<<4) + c;
    if (quad < 2 && m < 63){
      const float* rp = dobs + item*882 + m*14 + (quad<<3);
      float e[8];
      f32x2 p0 = *(const f32x2*)(rp);
      f32x2 p1 = *(const f32x2*)(rp+2);
      f32x2 p2 = *(const f32x2*)(rp+4);
      e[0]=p0.x; e[1]=p0.y; e[2]=p1.x; e[3]=p1.y; e[4]=p2.x; e[5]=p2.y;
      if (quad == 0){
        f32x2 p3 = *(const f32x2*)(rp+6);
        e[6]=p3.x; e[7]=p3.y;
      } else {
        e[6]=0.f; e[7]=0.f;                   // k = 14,15 pad
      }
      for (int d0 = 0; d0 < 4; ++d0)
        split_pair(e[2*d0], e[2*d0+1], ahi[d0], alo[d0]);
    }
  }
  __syncthreads();   // [S1] bits ready

  // ---------- degrees from popcount (adjacency exactly binary) ----------
  if (t < 64){
    unsigned long long mk = lds_Abits[t];
    int deg = __popcll(mk);
    lds_d[t] = 1.0f / sqrtf((float)(deg < 1 ? 1 : deg));
  }
  __syncthreads();   // [S2] d ready

  f32x4 d4v = *(const f32x4*)&lds_d[(w<<4) + (quad<<2)];
  const float dd[4] = {d4v.x, d4v.y, d4v.z, d4v.w};

  // ---------- expand this wave's A-frags from bitmask (held in regs, reused 3 layers) ----------
  U4 af0, af1;
  {
    unsigned long long mk = lds_Abits[(w<<4) + c];   // row 16w+c; 4-way broadcast per c
    unsigned blo = ((unsigned)mk) >> (quad<<3);        // bits for k = 8*quad + j
    unsigned bhi = ((unsigned)(mk >> 32)) >> (quad<<3);
    for (int r = 0; r < 4; ++r){
      unsigned e0 = 0u - ((blo >> (2*r)) & 1u);
      unsigned o0 = 0u - ((blo >> (2*r+1)) & 1u);
      af0.u[r] = (e0 & 0x3f80u) | (o0 & 0x3f800000u);
      unsigned e1 = 0u - ((bhi >> (2*r)) & 1u);
      unsigned o1 = 0u - ((bhi >> (2*r+1)) & 1u);
      af1.u[r] = (e1 & 0x3f80u) | (o1 & 0x3f800000u);
    }
  }

  // geometry for C-layout -> B-frag (Y) writes
  const int laneCy = c + ((w&1)<<5) + ((quad>>1)<<4);
  const int j0 = (quad&1)<<2;
  const int kspY = w>>1;
  unsigned short* Yhi = (unsigned short*)lds_R1;
  unsigned short* Ylo = ((unsigned short*)lds_R1) + 4096;

  float hcur[4][4];

  // ---------- embed: x = relu(dobs@Wdev + bdev); row63 = server; write Y1 = d*x ----------
  {
    U4 a_h, a_l;
    a_h.u = uint4v{ahi[0],ahi[1],ahi[2],ahi[3]};
    a_l.u = uint4v{alo[0],alo[1],alo[2],alo[3]};
    const uint4v* WdH = (const uint4v*)(ws + WS_WDEV_H);
    const uint4v* WdL = (const uint4v*)(ws + WS_WDEV_L);
    float srvv4[4];
    if (w == 3 && quad == 3){
      float s0 = sobs[item*3+0], s1v = sobs[item*3+1], s2v = sobs[item*3+2];
      for (int nt = 0; nt < 4; ++nt){
        int col = c + (nt<<4);
        float v = s0*Wsrv[col] + s1v*Wsrv[64+col] + s2v*Wsrv[128+col] + bsrv[col];
        srvv4[nt] = fmaxf(v, 0.f);
      }
    }
    for (int nt = 0; nt < 4; ++nt){
      U4 wh, wl;
      wh.u = WdH[(nt<<6) + lane];
      wl.u = WdL[(nt<<6) + lane];
      f32x4 g = {0.f,0.f,0.f,0.f};
      g = mfma16(a_h, wh, g);
      g = mfma16(a_h, wl, g);
      g = mfma16(a_l, wh, g);
      float bb = bdev[c + (nt<<4)];
      float y[4];
      for (int r = 0; r < 4; ++r) y[r] = fmaxf(g[r] + bb, 0.f);
      if (w == 3 && quad == 3) y[3] = srvv4[nt];    // row 63 = server embedding
      for (int r = 0; r < 4; ++r) y[r] *= dd[r];    // pre-scale by d^{-1/2}
      unsigned h01, l01, h23, l23;
      split_pair(y[0], y[1], h01, l01);
      split_pair(y[2], y[3], h23, l23);
      int base = ((((kspY<<2) + nt) << 6) + laneCy)*8 + j0;
      *(uint2v*)&Yhi[base] = uint2v{ h01, h23 };
      *(uint2v*)&Ylo[base] = uint2v{ l01, l23 };
    }
  }
  __syncthreads();   // Y1 ready

  // ---------- 3 GCN layers ----------
  const uint4v* WH_tab[3] = {(const uint4v*)(ws+WS_W1_H),(const uint4v*)(ws+WS_W2_H),(const uint4v*)(ws+WS_W3_H)};
  const uint4v* WL_tab[3] = {(const uint4v*)(ws+WS_W1_L),(const uint4v*)(ws+WS_W2_L),(const uint4v*)(ws+WS_W3_L)};
  const float* bias_tab[3] = {b1, b2, b3};

  unsigned* zbuf = lds_R1 + (w<<10);                 // per-wave 4 KB transpose slice
  const int piL = (lane>>2) | ((lane&3)<<4);         // bit-rotate swizzle
  const int s0L = (piL>>2) & 1;

  for (int L = 0; L < 3; ++L){
    // step 1: Z = A @ Y   (A binary exact; Y split hi+lo -> 2 passes)
    const uint4v* Yhi4 = (const uint4v*)lds_R1;
    const uint4v* Ylo4 = ((const uint4v*)lds_R1) + 512;
    f32x4 zacc[4];
    for (int nt = 0; nt < 4; ++nt){
      f32x4 g = {0.f,0.f,0.f,0.f};
      U4 yh, yl;
      yh.u = Yhi4[(0*4+nt)*64 + lane]; yl.u = Ylo4[(0*4+nt)*64 + lane];
      g = mfma16(af0, yh, g); g = mfma16(af0, yl, g);
      yh.u = Yhi4[(1*4+nt)*64 + lane]; yl.u = Ylo4[(1*4+nt)*64 + lane];
      g = mfma16(af1, yh, g); g = mfma16(af1, yl, g);
      zacc[nt] = g;
    }
    __syncthreads();  // [B2] all Y reads done; region reusable

    // step 2+3: Z' = d*Z, transpose C-layout -> A-frag via pi-swizzled PER-WAVE slice
    for (int nt = 0; nt < 4; ++nt){
      int ks = nt >> 1;
      int lcBase = (quad<<2) + ((((nt&1)<<1) + (c>>3)) << 4);
      int e = c & 7;
      for (int r = 0; r < 4; ++r){
        unsigned pk = pack_hl(zacc[nt][r] * dd[r]);
        int lane_c = lcBase + r;
        int pi = (lane_c>>2) | ((lane_c&3)<<4);
        int sel = ((e>>2) ^ (pi>>2)) & 1;
        zbuf[(ks<<9) + (pi<<3) + (sel<<2) + (e&3)] = pk;
      }
    }
    __threadfence_block();   // wave-private slice: order writes before reads
    U4 zh[2], zl[2];
    for (int ks = 0; ks < 2; ++ks){
      uint4v qa = *(const uint4v*)&zbuf[(ks<<9) + (piL<<3) + (s0L<<2)];
      uint4v qb = *(const uint4v*)&zbuf[(ks<<9) + (piL<<3) + ((1-s0L)<<2)];
      zh[ks].u = uint4v{ (qa.y<<16)|(qa.x&0xffffu), (qa.w<<16)|(qa.z&0xffffu),
                         (qb.y<<16)|(qb.x&0xffffu), (qb.w<<16)|(qb.z&0xffffu) };
      zl[ks].u = uint4v{ (qa.y&0xffff0000u)|(qa.x>>16), (qa.w&0xffff0000u)|(qa.z>>16),
                         (qb.y&0xffff0000u)|(qb.x>>16), (qb.w&0xffff0000u)|(qb.z>>16) };
    }

    // step 4+5: G = Z' @ W (3-pass split), h = relu(G + b)
    const uint4v* WHp = WH_tab[L];
    const uint4v* WLp = WL_tab[L];
    const float* bp = bias_tab[L];
    for (int nt = 0; nt < 4; ++nt){
      f32x4 g = {0.f,0.f,0.f,0.f};
      for (int ks = 0; ks < 2; ++ks){
        U4 wh, wl;
        wh.u = WHp[((ks<<2)+nt)*64 + lane];
        wl.u = WLp[((ks<<2)+nt)*64 + lane];
        g = mfma16(zh[ks], wh, g);
        g = mfma16(zh[ks], wl, g);
        g = mfma16(zl[ks], wh, g);
      }
      float bb = bp[c + (nt<<4)];
      for (int r = 0; r < 4; ++r) hcur[nt][r] = fmaxf(g[r] + bb, 0.f);
    }
    __syncthreads();  // [B3] all Z' reads done; region reusable

    if (L < 2){
      // step 6: write next Y = d * h
      for (int nt = 0; nt < 4; ++nt){
        unsigned h01, l01, h23, l23;
        split_pair(hcur[nt][0]*dd[0], hcur[nt][1]*dd[1], h01, l01);
        split_pair(hcur[nt][2]*dd[2], hcur[nt][3]*dd[3], h23, l23);
        int base = ((((kspY<<2) + nt) << 6) + laneCy)*8 + j0;
        *(uint2v*)&Yhi[base] = uint2v{ h01, h23 };
        *(uint2v*)&Ylo[base] = uint2v{ l01, l23 };
      }
      __syncthreads();  // next layer's Y ready
    }
  }

  // ---------- head ----------
  // col-sum partials (quad-reduced in-wave) + server row; h -> A-frag transpose in zbuf
  {
    bool isSrvLane = (w == 3) && (quad == 3);
    float cs[4];
    for (int nt = 0; nt < 4; ++nt){
      float s = hcur[nt][0] + hcur[nt][1] + hcur[nt][2] + hcur[nt][3];
      if (isSrvLane){ s -= hcur[nt][3]; lds_srv[c + (nt<<4)] = hcur[nt][3]; }
      s += __shfl_xor(s, 16);
      s += __shfl_xor(s, 32);
      cs[nt] = s;
    }
    if (quad == 0)
      for (int nt = 0; nt < 4; ++nt) lds_mp[(w<<6) + c + (nt<<4)] = cs[nt];
  }
  for (int nt = 0; nt < 4; ++nt){
    int ks = nt >> 1;
    int lcBase = (quad<<2) + ((((nt&1)<<1) + (c>>3)) << 4);
    int e = c & 7;
    for (int r = 0; r < 4; ++r){
      unsigned pk = pack_hl(hcur[nt][r]);
      int lane_c = lcBase + r;
      int pi = (lane_c>>2) | ((lane_c&3)<<4);
      int sel = ((e>>2) ^ (pi>>2)) & 1;
      zbuf[(ks<<9) + (pi<<3) + (sel<<2) + (e&3)] = pk;
    }
  }
  __syncthreads();  // [Bh1] partials + srv + zbuf writes done

  // V = [mean(63 dev rows); srv] split to bf16 hi/lo in LDS
  if (t < 64){
    float mv = (lds_mp[t] + lds_mp[64+t] + lds_mp[128+t] + lds_mp[192+t]) * (1.0f/63.0f);
    unsigned short h,l; split2(mv,h,l);
    lds_Vh[t]=h; lds_Vl[t]=l;
  } else if (t < 128){
    float sv = lds_srv[t-64];
    unsigned short h,l; split2(sv,h,l);
    lds_Vh[t]=h; lds_Vl[t]=l;
  }
  __syncthreads();  // [Bh2] V ready (zbuf reads safe: 2 barriers after writes)

  // read back h A-frags
  U4 hh[2], hl[2];
  for (int ks = 0; ks < 2; ++ks){
    uint4v qa = *(const uint4v*)&zbuf[(ks<<9) + (piL<<3) + (s0L<<2)];
    uint4v qb = *(const uint4v*)&zbuf[(ks<<9) + (piL<<3) + ((1-s0L)<<2)];
    hh[ks].u = uint4v{ (qa.y<<16)|(qa.x&0xffffu), (qa.w<<16)|(qa.z&0xffffu),
                       (qb.y<<16)|(qb.x&0xffffu), (qb.w<<16)|(qb.z&0xffffu) };
    hl[ks].u = uint4v{ (qa.y&0xffff0000u)|(qa.x>>16), (qa.w&0xffff0000u)|(qa.z>>16),
                       (qb.y&0xffff0000u)|(qb.x>>16), (qb.w&0xffff0000u)|(qb.z>>16) };
  }

  // s1 = V @ Wfull + bf1 via MFMA (row 0 only); wave w owns cols 32w..32w+31
  {
    const uint4v* WfH = (const uint4v*)(ws + WS_WF_H);
    const uint4v* WfL = (const uint4v*)(ws + WS_WF_L);
    f32x4 sacc0 = {0.f,0.f,0.f,0.f}, sacc1 = {0.f,0.f,0.f,0.f};
    for (int ks = 0; ks < 4; ++ks){
      U4 vh, vl;
      vh.u = *(const uint4v*)((const char*)lds_Vh + (ks<<6) + (quad<<4));
      vl.u = *(const uint4v*)((const char*)lds_Vl + (ks<<6) + (quad<<4));
      if (c != 0){ vh.u = uint4v{0,0,0,0}; vl.u = uint4v{0,0,0,0}; }
      int nt0 = (w<<1);
      U4 wh, wl;
      wh.u = WfH[((ks<<3)+nt0)*64 + lane];
      wl.u = WfL[((ks<<3)+nt0)*64 + lane];
      sacc0 = mfma16(vh, wh, sacc0);
      sacc0 = mfma16(vh, wl, sacc0);
      sacc0 = mfma16(vl, wh, sacc0);
      wh.u = WfH[((ks<<3)+nt0+1)*64 + lane];
      wl.u = WfL[((ks<<3)+nt0+1)*64 + lane];
      sacc1 = mfma16(vh, wh, sacc1);
      sacc1 = mfma16(vh, wl, sacc1);
      sacc1 = mfma16(vl, wh, sacc1);
    }
    if (quad == 0){
      int col0 = c + (w<<5);
      lds_s1[col0]      = sacc0[0] + bf1[col0];
      lds_s1[col0 + 16] = sacc1[0] + bf1[col0 + 16];
    }
  }
  __syncthreads();  // [Bh3] s1 ready

  // P = h @ Wa (3-pass split), epilogue: out_n = sum_j relu(P+s1)[j]*Wf2[j]
  const uint4v* WaH = (const uint4v*)(ws + WS_WA_H);
  const uint4v* WaL = (const uint4v*)(ws + WS_WA_L);
  float outacc[4] = {0.f,0.f,0.f,0.f};
  for (int nt = 0; nt < 8; ++nt){
    f32x4 g = {0.f,0.f,0.f,0.f};
    for (int ks = 0; ks < 2; ++ks){
      U4 wh, wl;
      wh.u = WaH[((ks<<3)+nt)*64 + lane];
      wl.u = WaL[((ks<<3)+nt)*64 + lane];
      g = mfma16(hh[ks], wh, g);
      g = mfma16(hh[ks], wl, g);
      g = mfma16(hl[ks], wh, g);
    }
    int col = c + (nt<<4);
    float sv = lds_s1[col];
    float w2 = Wf2[col];
    for (int r = 0; r < 4; ++r){
      float zz = fmaxf(g[r] + sv, 0.f);
      outacc[r] += zz * w2;
    }
  }
  {
    float bb = bf2[0];
    for (int r = 0; r < 4; ++r){
      float v = outacc[r];
      v += __shfl_xor(v, 1); v += __shfl_xor(v, 2);
      v += __shfl_xor(v, 4); v += __shfl_xor(v, 8);
      if (c == 0){
        int row = (w<<4) + (quad<<2) + r;
        if (row < 63) out[item*63 + row] = v + bb;
      }
    }
  }
}

extern "C" void kernel_launch(void* const* d_in, const int* in_sizes, int n_in,
                              void* d_out, int out_size, void* d_ws, size_t ws_size,
                              hipStream_t stream)
{
  const float* dobs = (const float*)d_in[0];
  const float* sobs = (const float*)d_in[1];
  const float* adj  = (const float*)d_in[2];
  const float* Wdev = (const float*)d_in[3];
  const float* bdev = (const float*)d_in[4];
  const float* Wsrv = (const float*)d_in[5];
  const float* bsrv = (const float*)d_in[6];
  const float* W1   = (const float*)d_in[7];
  const float* b1   = (const float*)d_in[8];
  const float* W2   = (const float*)d_in[9];
  const float* b2   = (const float*)d_in[10];
  const float* W3   = (const float*)d_in[11];
  const float* b3   = (const float*)d_in[12];
  const float* Wf1  = (const float*)d_in[13];
  const float* bf1  = (const float*)d_in[14];
  const float* Wf2  = (const float*)d_in[15];
  const float* bf2  = (const float*)d_in[16];
  float* out = (float*)d_out;
  char* ws = (char*)d_ws;
  int nb = in_sizes[1] / 3;   // batch size (server_obs is B x 3)

  prep_weights<<<dim3(160), dim3(256), 0, stream>>>(Wdev, W1, W2, W3, Wf1, ws);
  pgcn_fused<<<dim3(nb), dim3(256), 0, stream>>>(dobs, sobs, adj, bdev, Wsrv, bsrv,
                                                 b1, b2, b3, bf1, Wf2, bf2, ws, out);
}

// Round 5
// 635.363 us; speedup vs baseline: 1.2471x; 1.1847x over previous
//
#include <hip/hip_runtime.h>
#include <stdint.h>

typedef __attribute__((ext_vector_type(8))) __bf16 bf16x8;
typedef __attribute__((ext_vector_type(4))) float f32x4;
typedef __attribute__((ext_vector_type(2))) float f32x2;
typedef __attribute__((ext_vector_type(4))) unsigned uint4v;
typedef __attribute__((ext_vector_type(2))) unsigned uint2v;

union U4 { uint4v u; bf16x8 b; };

// ---- d_ws layout (bytes) ----
#define WS_WDEV_H 0
#define WS_WDEV_L 4096
#define WS_W1_H   8192
#define WS_W1_L   16384
#define WS_W2_H   24576
#define WS_W2_L   32768
#define WS_W3_H   40960
#define WS_W3_L   49152
#define WS_WA_H   57344
#define WS_WA_L   73728
#define WS_WF_H   90112
#define WS_WF_L   122880
// total 155648 bytes

__device__ __forceinline__ unsigned short f2bf(float f){
  union { float f; unsigned u; } v; v.f = f;
  unsigned r = v.u + 0x7fffu + ((v.u >> 16) & 1u);
  return (unsigned short)(r >> 16);
}
__device__ __forceinline__ float bf2f(unsigned short h){
  union { unsigned u; float f; } v; v.u = ((unsigned)h) << 16; return v.f;
}
__device__ __forceinline__ void split2(float x, unsigned short& hi, unsigned short& lo){
  hi = f2bf(x);
  lo = f2bf(x - bf2f(hi));   // exact residual
}
__device__ __forceinline__ f32x4 mfma16(const U4& a, const U4& b, f32x4 c){
  return __builtin_amdgcn_mfma_f32_16x16x32_bf16(a.b, b.b, c, 0, 0, 0);
}

// ---- fast RN-bf16 split/pack helpers ----
__device__ __forceinline__ unsigned rnu(unsigned u){
  return u + 0x7fffu + ((u >> 16) & 1u);
}
__device__ __forceinline__ void split_pair(float x0, float x1, unsigned& hi2, unsigned& lo2){
  unsigned r0 = rnu(__float_as_uint(x0)), r1 = rnu(__float_as_uint(x1));
  float l0 = x0 - __uint_as_float(r0 & 0xffff0000u);
  float l1 = x1 - __uint_as_float(r1 & 0xffff0000u);
  hi2 = __builtin_amdgcn_perm(r1, r0, 0x07060302u);
  unsigned s0 = rnu(__float_as_uint(l0)), s1 = rnu(__float_as_uint(l1));
  lo2 = __builtin_amdgcn_perm(s1, s0, 0x07060302u);
}
__device__ __forceinline__ unsigned pack_hl(float z){
  unsigned r = rnu(__float_as_uint(z));
  float lf = z - __uint_as_float(r & 0xffff0000u);
  unsigned s = rnu(__float_as_uint(lf));
  return __builtin_amdgcn_perm(s, r, 0x07060302u);    // low16=hi(z), high16=lo(z)
}

// ------------------------------------------------------------------
// prep kernel: weights -> hi/lo bf16 MFMA B-fragments.
// B-frag: idx = ((ks*NT+nt)*64 + lane)*8 + j ; k = ks*32+(lane>>4)*8+j, n = nt*16+(lane&15)
// ------------------------------------------------------------------
extern "C" __global__ void prep_weights(const float* __restrict__ Wdev,
                                        const float* __restrict__ W1,
                                        const float* __restrict__ W2,
                                        const float* __restrict__ W3,
                                        const float* __restrict__ Wf1,
                                        char* __restrict__ ws)
{
  unsigned short* WdevH = (unsigned short*)(ws + WS_WDEV_H);
  unsigned short* WdevL = (unsigned short*)(ws + WS_WDEV_L);
  unsigned short* WH[3] = {(unsigned short*)(ws+WS_W1_H),(unsigned short*)(ws+WS_W2_H),(unsigned short*)(ws+WS_W3_H)};
  unsigned short* WL[3] = {(unsigned short*)(ws+WS_W1_L),(unsigned short*)(ws+WS_W2_L),(unsigned short*)(ws+WS_W3_L)};
  unsigned short* WaH = (unsigned short*)(ws + WS_WA_H);
  unsigned short* WaL = (unsigned short*)(ws + WS_WA_L);
  unsigned short* WfH = (unsigned short*)(ws + WS_WF_H);
  unsigned short* WfL = (unsigned short*)(ws + WS_WF_L);
  const int total = 2048 + 3*4096 + 8192 + 16384;
  for (int idx = blockIdx.x*256 + threadIdx.x; idx < total; idx += gridDim.x*256){
    if (idx < 2048){                       // Wdev (14x64), K padded to 32, NT=4
      int tt = idx;
      int frag = tt >> 9, within = tt & 511, lane = within >> 3, j = within & 7;
      int nt = frag & 3;
      int k = ((lane>>4)<<3) + j;
      int n = (nt<<4) + (lane & 15);
      float v = (k < 14) ? Wdev[k*64 + n] : 0.f;
      unsigned short h,l; split2(v,h,l); WdevH[tt]=h; WdevL[tt]=l;
    } else if (idx < 2048 + 3*4096){       // W1/W2/W3 (64x64), KS=2, NT=4
      int tt = idx - 2048; int Li = tt / 4096; int r = tt - Li*4096;
      int frag = r >> 9, within = r & 511, lane = within >> 3, j = within & 7;
      int ks = frag >> 2, nt = frag & 3;
      int k = (ks<<5) + ((lane>>4)<<3) + j;
      int n = (nt<<4) + (lane & 15);
      const float* W = (Li==0) ? W1 : ((Li==1) ? W2 : W3);
      float v = W[k*64 + n];
      unsigned short h,l; split2(v,h,l); WH[Li][r]=h; WL[Li][r]=l;
    } else if (idx < 2048 + 3*4096 + 8192){ // Wa = Wf1 rows 0..63 (64x128), KS=2, NT=8
      int r = idx - (2048 + 3*4096);
      int frag = r >> 9, within = r & 511, lane = within >> 3, j = within & 7;
      int ks = frag >> 3, nt = frag & 7;
      int k = (ks<<5) + ((lane>>4)<<3) + j;
      int n = (nt<<4) + (lane & 15);
      float v = Wf1[k*128 + n];
      unsigned short h,l; split2(v,h,l); WaH[r]=h; WaL[r]=l;
    } else {                                // Wfull = Wf1 rows 64..191 (128x128), KS=4, NT=8
      int r = idx - (2048 + 3*4096 + 8192);
      int frag = r >> 9, within = r & 511, lane = within >> 3, j = within & 7;
      int ks = frag >> 3, nt = frag & 7;
      int k = (ks<<5) + ((lane>>4)<<3) + j;
      int n = (nt<<4) + (lane & 15);
      float v = Wf1[(64 + k)*128 + n];
      unsigned short h,l; split2(v,h,l); WfH[r]=h; WfL[r]=l;
    }
  }
}

// ------------------------------------------------------------------
// fused PGCN critic: one block per batch item, wave w owns rows 16w..16w+15
// launch_bounds(256,6): 6 waves/EU -> VGPR+AGPR cap ~84/wave, NO scratch spills
// (R4's (256,8) capped at 64 regs incl. AGPRs -> 700 MB/dispatch spill traffic)
// ------------------------------------------------------------------
extern "C" __global__ __launch_bounds__(256, 6)
void pgcn_fused(const float* __restrict__ dobs, const float* __restrict__ sobs,
                const float* __restrict__ adj,
                const float* __restrict__ bdev,
                const float* __restrict__ Wsrv, const float* __restrict__ bsrv,
                const float* __restrict__ b1, const float* __restrict__ b2,
                const float* __restrict__ b3,
                const float* __restrict__ bf1, const float* __restrict__ Wf2,
                const float* __restrict__ bf2,
                const char* __restrict__ ws, float* __restrict__ out)
{
  __shared__ __align__(16) unsigned long long lds_Abits[64];  // 512 B adjacency bitmask
  __shared__ __align__(16) float    lds_d[64];                // d^{-1/2}
  __shared__ __align__(16) unsigned lds_R1[4096];             // 16 KB: Y hi|lo B-frags / per-wave zbuf
  __shared__ __align__(16) float    lds_mp[256];              // per-wave col-sum partials
  __shared__ __align__(16) float    lds_srv[64];
  __shared__ __align__(16) float    lds_s1[128];
  __shared__ __align__(16) unsigned short lds_Vh[128];
  __shared__ __align__(16) unsigned short lds_Vl[128];

  const int t = threadIdx.x;
  const int w = t >> 6;
  const int lane = t & 63;
  const int quad = lane >> 4;
  const int c = lane & 15;
  const long item = blockIdx.x;

  // ---------- stage adjacency as bitmask: thread t -> row t>>2, 16-col chunk t&3 ----------
  {
    const f32x4* src = (const f32x4*)(adj + item*4096 + ((t>>2)<<6) + ((t&3)<<4));
    unsigned bits = 0;
    for (int i = 0; i < 4; ++i){
      f32x4 v = src[i];
      unsigned b = (v.x != 0.f) | (((unsigned)(v.y != 0.f))<<1)
                 | (((unsigned)(v.z != 0.f))<<2) | (((unsigned)(v.w != 0.f))<<3);
      bits |= b << (i<<2);
    }
    ((unsigned short*)lds_Abits)[t] = (unsigned short)bits;
  }

  // ---------- load device_obs rows as A-operand frags (hi/lo) ----------
  unsigned ahi[4] = {0,0,0,0}, alo[4] = {0,0,0,0};
  {
    int m = (w<<4) + c;
    if (quad < 2 && m < 63){
      const float* rp = dobs + item*882 + m*14 + (quad<<3);
      float e[8];
      f32x2 p0 = *(const f32x2*)(rp);
      f32x2 p1 = *(const f32x2*)(rp+2);
      f32x2 p2 = *(const f32x2*)(rp+4);
      e[0]=p0.x; e[1]=p0.y; e[2]=p1.x; e[3]=p1.y; e[4]=p2.x; e[5]=p2.y;
      if (quad == 0){
        f32x2 p3 = *(const f32x2*)(rp+6);
        e[6]=p3.x; e[7]=p3.y;
      } else {
        e[6]=0.f; e[7]=0.f;                   // k = 14,15 pad
      }
      for (int d0 = 0; d0 < 4; ++d0)
        split_pair(e[2*d0], e[2*d0+1], ahi[d0], alo[d0]);
    }
  }
  __syncthreads();   // [S1] bits ready

  // ---------- degrees from popcount (adjacency exactly binary) ----------
  if (t < 64){
    unsigned long long mk = lds_Abits[t];
    int deg = __popcll(mk);
    lds_d[t] = 1.0f / sqrtf((float)(deg < 1 ? 1 : deg));
  }
  __syncthreads();   // [S2] d ready

  f32x4 d4v = *(const f32x4*)&lds_d[(w<<4) + (quad<<2)];
  const float dd[4] = {d4v.x, d4v.y, d4v.z, d4v.w};

  // ---------- expand this wave's A-frags from bitmask (held in regs, reused 3 layers) ----------
  U4 af0, af1;
  {
    unsigned long long mk = lds_Abits[(w<<4) + c];   // row 16w+c; 4-way broadcast per c
    unsigned blo = ((unsigned)mk) >> (quad<<3);        // bits for k = 8*quad + j
    unsigned bhi = ((unsigned)(mk >> 32)) >> (quad<<3);
    for (int r = 0; r < 4; ++r){
      unsigned e0 = 0u - ((blo >> (2*r)) & 1u);
      unsigned o0 = 0u - ((blo >> (2*r+1)) & 1u);
      af0.u[r] = (e0 & 0x3f80u) | (o0 & 0x3f800000u);
      unsigned e1 = 0u - ((bhi >> (2*r)) & 1u);
      unsigned o1 = 0u - ((bhi >> (2*r+1)) & 1u);
      af1.u[r] = (e1 & 0x3f80u) | (o1 & 0x3f800000u);
    }
  }

  // geometry for C-layout -> B-frag (Y) writes
  const int laneCy = c + ((w&1)<<5) + ((quad>>1)<<4);
  const int j0 = (quad&1)<<2;
  const int kspY = w>>1;
  unsigned short* Yhi = (unsigned short*)lds_R1;
  unsigned short* Ylo = ((unsigned short*)lds_R1) + 4096;

  float hcur[4][4];

  // ---------- embed: x = relu(dobs@Wdev + bdev); row63 = server; write Y1 = d*x ----------
  {
    U4 a_h, a_l;
    a_h.u = uint4v{ahi[0],ahi[1],ahi[2],ahi[3]};
    a_l.u = uint4v{alo[0],alo[1],alo[2],alo[3]};
    const uint4v* WdH = (const uint4v*)(ws + WS_WDEV_H);
    const uint4v* WdL = (const uint4v*)(ws + WS_WDEV_L);
    float srvv4[4];
    if (w == 3 && quad == 3){
      float s0 = sobs[item*3+0], s1v = sobs[item*3+1], s2v = sobs[item*3+2];
      for (int nt = 0; nt < 4; ++nt){
        int col = c + (nt<<4);
        float v = s0*Wsrv[col] + s1v*Wsrv[64+col] + s2v*Wsrv[128+col] + bsrv[col];
        srvv4[nt] = fmaxf(v, 0.f);
      }
    }
    for (int nt = 0; nt < 4; ++nt){
      U4 wh, wl;
      wh.u = WdH[(nt<<6) + lane];
      wl.u = WdL[(nt<<6) + lane];
      f32x4 g = {0.f,0.f,0.f,0.f};
      g = mfma16(a_h, wh, g);
      g = mfma16(a_h, wl, g);
      g = mfma16(a_l, wh, g);
      float bb = bdev[c + (nt<<4)];
      float y[4];
      for (int r = 0; r < 4; ++r) y[r] = fmaxf(g[r] + bb, 0.f);
      if (w == 3 && quad == 3) y[3] = srvv4[nt];    // row 63 = server embedding
      for (int r = 0; r < 4; ++r) y[r] *= dd[r];    // pre-scale by d^{-1/2}
      unsigned h01, l01, h23, l23;
      split_pair(y[0], y[1], h01, l01);
      split_pair(y[2], y[3], h23, l23);
      int base = ((((kspY<<2) + nt) << 6) + laneCy)*8 + j0;
      *(uint2v*)&Yhi[base] = uint2v{ h01, h23 };
      *(uint2v*)&Ylo[base] = uint2v{ l01, l23 };
    }
  }
  __syncthreads();   // Y1 ready

  // ---------- 3 GCN layers ----------
  const uint4v* WH_tab[3] = {(const uint4v*)(ws+WS_W1_H),(const uint4v*)(ws+WS_W2_H),(const uint4v*)(ws+WS_W3_H)};
  const uint4v* WL_tab[3] = {(const uint4v*)(ws+WS_W1_L),(const uint4v*)(ws+WS_W2_L),(const uint4v*)(ws+WS_W3_L)};
  const float* bias_tab[3] = {b1, b2, b3};

  unsigned* zbuf = lds_R1 + (w<<10);                 // per-wave 4 KB transpose slice
  const int piL = (lane>>2) | ((lane&3)<<4);         // bit-rotate swizzle
  const int s0L = (piL>>2) & 1;

  for (int L = 0; L < 3; ++L){
    // step 1: Z = A @ Y   (A binary exact; Y split hi+lo -> 2 passes)
    const uint4v* Yhi4 = (const uint4v*)lds_R1;
    const uint4v* Ylo4 = ((const uint4v*)lds_R1) + 512;
    f32x4 zacc[4];
    for (int nt = 0; nt < 4; ++nt){
      f32x4 g = {0.f,0.f,0.f,0.f};
      U4 yh, yl;
      yh.u = Yhi4[(0*4+nt)*64 + lane]; yl.u = Ylo4[(0*4+nt)*64 + lane];
      g = mfma16(af0, yh, g); g = mfma16(af0, yl, g);
      yh.u = Yhi4[(1*4+nt)*64 + lane]; yl.u = Ylo4[(1*4+nt)*64 + lane];
      g = mfma16(af1, yh, g); g = mfma16(af1, yl, g);
      zacc[nt] = g;
    }
    __syncthreads();  // [B2] all Y reads done; region reusable

    // step 2+3: Z' = d*Z, transpose C-layout -> A-frag via pi-swizzled PER-WAVE slice
    for (int nt = 0; nt < 4; ++nt){
      int ks = nt >> 1;
      int lcBase = (quad<<2) + ((((nt&1)<<1) + (c>>3)) << 4);
      int e = c & 7;
      for (int r = 0; r < 4; ++r){
        unsigned pk = pack_hl(zacc[nt][r] * dd[r]);
        int lane_c = lcBase + r;
        int pi = (lane_c>>2) | ((lane_c&3)<<4);
        int sel = ((e>>2) ^ (pi>>2)) & 1;
        zbuf[(ks<<9) + (pi<<3) + (sel<<2) + (e&3)] = pk;
      }
    }
    __threadfence_block();   // wave-private slice: order writes before reads
    U4 zh[2], zl[2];
    for (int ks = 0; ks < 2; ++ks){
      uint4v qa = *(const uint4v*)&zbuf[(ks<<9) + (piL<<3) + (s0L<<2)];
      uint4v qb = *(const uint4v*)&zbuf[(ks<<9) + (piL<<3) + ((1-s0L)<<2)];
      zh[ks].u = uint4v{ (qa.y<<16)|(qa.x&0xffffu), (qa.w<<16)|(qa.z&0xffffu),
                         (qb.y<<16)|(qb.x&0xffffu), (qb.w<<16)|(qb.z&0xffffu) };
      zl[ks].u = uint4v{ (qa.y&0xffff0000u)|(qa.x>>16), (qa.w&0xffff0000u)|(qa.z>>16),
                         (qb.y&0xffff0000u)|(qb.x>>16), (qb.w&0xffff0000u)|(qb.z>>16) };
    }

    // step 4+5: G = Z' @ W (3-pass split), h = relu(G + b)
    const uint4v* WHp = WH_tab[L];
    const uint4v* WLp = WL_tab[L];
    const float* bp = bias_tab[L];
    for (int nt = 0; nt < 4; ++nt){
      f32x4 g = {0.f,0.f,0.f,0.f};
      for (int ks = 0; ks < 2; ++ks){
        U4 wh, wl;
        wh.u = WHp[((ks<<2)+nt)*64 + lane];
        wl.u = WLp[((ks<<2)+nt)*64 + lane];
        g = mfma16(zh[ks], wh, g);
        g = mfma16(zh[ks], wl, g);
        g = mfma16(zl[ks], wh, g);
      }
      float bb = bp[c + (nt<<4)];
      for (int r = 0; r < 4; ++r) hcur[nt][r] = fmaxf(g[r] + bb, 0.f);
    }
    __syncthreads();  // [B3] all Z' reads done; region reusable

    if (L < 2){
      // step 6: write next Y = d * h
      for (int nt = 0; nt < 4; ++nt){
        unsigned h01, l01, h23, l23;
        split_pair(hcur[nt][0]*dd[0], hcur[nt][1]*dd[1], h01, l01);
        split_pair(hcur[nt][2]*dd[2], hcur[nt][3]*dd[3], h23, l23);
        int base = ((((kspY<<2) + nt) << 6) + laneCy)*8 + j0;
        *(uint2v*)&Yhi[base] = uint2v{ h01, h23 };
        *(uint2v*)&Ylo[base] = uint2v{ l01, l23 };
      }
      __syncthreads();  // next layer's Y ready
    }
  }

  // ---------- head ----------
  // col-sum partials (quad-reduced in-wave) + server row; h -> A-frag transpose in zbuf
  {
    bool isSrvLane = (w == 3) && (quad == 3);
    float cs[4];
    for (int nt = 0; nt < 4; ++nt){
      float s = hcur[nt][0] + hcur[nt][1] + hcur[nt][2] + hcur[nt][3];
      if (isSrvLane){ s -= hcur[nt][3]; lds_srv[c + (nt<<4)] = hcur[nt][3]; }
      s += __shfl_xor(s, 16);
      s += __shfl_xor(s, 32);
      cs[nt] = s;
    }
    if (quad == 0)
      for (int nt = 0; nt < 4; ++nt) lds_mp[(w<<6) + c + (nt<<4)] = cs[nt];
  }
  for (int nt = 0; nt < 4; ++nt){
    int ks = nt >> 1;
    int lcBase = (quad<<2) + ((((nt&1)<<1) + (c>>3)) << 4);
    int e = c & 7;
    for (int r = 0; r < 4; ++r){
      unsigned pk = pack_hl(hcur[nt][r]);
      int lane_c = lcBase + r;
      int pi = (lane_c>>2) | ((lane_c&3)<<4);
      int sel = ((e>>2) ^ (pi>>2)) & 1;
      zbuf[(ks<<9) + (pi<<3) + (sel<<2) + (e&3)] = pk;
    }
  }
  __syncthreads();  // [Bh1] partials + srv + zbuf writes done

  // V = [mean(63 dev rows); srv] split to bf16 hi/lo in LDS
  if (t < 64){
    float mv = (lds_mp[t] + lds_mp[64+t] + lds_mp[128+t] + lds_mp[192+t]) * (1.0f/63.0f);
    unsigned short h,l; split2(mv,h,l);
    lds_Vh[t]=h; lds_Vl[t]=l;
  } else if (t < 128){
    float sv = lds_srv[t-64];
    unsigned short h,l; split2(sv,h,l);
    lds_Vh[t]=h; lds_Vl[t]=l;
  }
  __syncthreads();  // [Bh2] V ready (zbuf reads safe: 2 barriers after writes)

  // read back h A-frags
  U4 hh[2], hl[2];
  for (int ks = 0; ks < 2; ++ks){
    uint4v qa = *(const uint4v*)&zbuf[(ks<<9) + (piL<<3) + (s0L<<2)];
    uint4v qb = *(const uint4v*)&zbuf[(ks<<9) + (piL<<3) + ((1-s0L)<<2)];
    hh[ks].u = uint4v{ (qa.y<<16)|(qa.x&0xffffu), (qa.w<<16)|(qa.z&0xffffu),
                       (qb.y<<16)|(qb.x&0xffffu), (qb.w<<16)|(qb.z&0xffffu) };
    hl[ks].u = uint4v{ (qa.y&0xffff0000u)|(qa.x>>16), (qa.w&0xffff0000u)|(qa.z>>16),
                       (qb.y&0xffff0000u)|(qb.x>>16), (qb.w&0xffff0000u)|(qb.z>>16) };
  }

  // s1 = V @ Wfull + bf1 via MFMA (row 0 only); wave w owns cols 32w..32w+31
  {
    const uint4v* WfH = (const uint4v*)(ws + WS_WF_H);
    const uint4v* WfL = (const uint4v*)(ws + WS_WF_L);
    f32x4 sacc0 = {0.f,0.f,0.f,0.f}, sacc1 = {0.f,0.f,0.f,0.f};
    for (int ks = 0; ks < 4; ++ks){
      U4 vh, vl;
      vh.u = *(const uint4v*)((const char*)lds_Vh + (ks<<6) + (quad<<4));
      vl.u = *(const uint4v*)((const char*)lds_Vl + (ks<<6) + (quad<<4));
      if (c != 0){ vh.u = uint4v{0,0,0,0}; vl.u = uint4v{0,0,0,0}; }
      int nt0 = (w<<1);
      U4 wh, wl;
      wh.u = WfH[((ks<<3)+nt0)*64 + lane];
      wl.u = WfL[((ks<<3)+nt0)*64 + lane];
      sacc0 = mfma16(vh, wh, sacc0);
      sacc0 = mfma16(vh, wl, sacc0);
      sacc0 = mfma16(vl, wh, sacc0);
      wh.u = WfH[((ks<<3)+nt0+1)*64 + lane];
      wl.u = WfL[((ks<<3)+nt0+1)*64 + lane];
      sacc1 = mfma16(vh, wh, sacc1);
      sacc1 = mfma16(vh, wl, sacc1);
      sacc1 = mfma16(vl, wh, sacc1);
    }
    if (quad == 0){
      int col0 = c + (w<<5);
      lds_s1[col0]      = sacc0[0] + bf1[col0];
      lds_s1[col0 + 16] = sacc1[0] + bf1[col0 + 16];
    }
  }
  __syncthreads();  // [Bh3] s1 ready

  // P = h @ Wa (3-pass split), epilogue: out_n = sum_j relu(P+s1)[j]*Wf2[j]
  const uint4v* WaH = (const uint4v*)(ws + WS_WA_H);
  const uint4v* WaL = (const uint4v*)(ws + WS_WA_L);
  float outacc[4] = {0.f,0.f,0.f,0.f};
  for (int nt = 0; nt < 8; ++nt){
    f32x4 g = {0.f,0.f,0.f,0.f};
    for (int ks = 0; ks < 2; ++ks){
      U4 wh, wl;
      wh.u = WaH[((ks<<3)+nt)*64 + lane];
      wl.u = WaL[((ks<<3)+nt)*64 + lane];
      g = mfma16(hh[ks], wh, g);
      g = mfma16(hh[ks], wl, g);
      g = mfma16(hl[ks], wh, g);
    }
    int col = c + (nt<<4);
    float sv = lds_s1[col];
    float w2 = Wf2[col];
    for (int r = 0; r < 4; ++r){
      float zz = fmaxf(g[r] + sv, 0.f);
      outacc[r] += zz * w2;
    }
  }
  {
    float bb = bf2[0];
    for (int r = 0; r < 4; ++r){
      float v = outacc[r];
      v += __shfl_xor(v, 1); v += __shfl_xor(v, 2);
      v += __shfl_xor(v, 4); v += __shfl_xor(v, 8);
      if (c == 0){
        int row = (w<<4) + (quad<<2) + r;
        if (row < 63) out[item*63 + row] = v + bb;
      }
    }
  }
}

extern "C" void kernel_launch(void* const* d_in, const int* in_sizes, int n_in,
                              void* d_out, int out_size, void* d_ws, size_t ws_size,
                              hipStream_t stream)
{
  const float* dobs = (const float*)d_in[0];
  const float* sobs = (const float*)d_in[1];
  const float* adj  = (const float*)d_in[2];
  const float* Wdev = (const float*)d_in[3];
  const float* bdev = (const float*)d_in[4];
  const float* Wsrv = (const float*)d_in[5];
  const float* bsrv = (const float*)d_in[6];
  const float* W1   = (const float*)d_in[7];
  const float* b1   = (const float*)d_in[8];
  const float* W2   = (const float*)d_in[9];
  const float* b2   = (const float*)d_in[10];
  const float* W3   = (const float*)d_in[11];
  const float* b3   = (const float*)d_in[12];
  const float* Wf1  = (const float*)d_in[13];
  const float* bf1  = (const float*)d_in[14];
  const float* Wf2  = (const float*)d_in[15];
  const float* bf2  = (const float*)d_in[16];
  float* out = (float*)d_out;
  char* ws = (char*)d_ws;
  int nb = in_sizes[1] / 3;   // batch size (server_obs is B x 3)

  prep_weights<<<dim3(160), dim3(256), 0, stream>>>(Wdev, W1, W2, W3, Wf1, ws);
  pgcn_fused<<<dim3(nb), dim3(256), 0, stream>>>(dobs, sobs, adj, bdev, Wsrv, bsrv,
                                                 b1, b2, b3, bf1, Wf2, bf2, ws, out);
}

// Round 6
// 630.229 us; speedup vs baseline: 1.2572x; 1.0081x over previous
//
#include <hip/hip_runtime.h>
#include <stdint.h>

typedef __attribute__((ext_vector_type(8))) __bf16 bf16x8;
typedef __attribute__((ext_vector_type(4))) float f32x4;
typedef __attribute__((ext_vector_type(2))) float f32x2;
typedef __attribute__((ext_vector_type(4))) unsigned uint4v;
typedef __attribute__((ext_vector_type(2))) unsigned uint2v;

union U4 { uint4v u; bf16x8 b; };

// ---- d_ws layout (bytes) ----
#define WS_WDEV_H 0
#define WS_WDEV_L 4096
#define WS_W1_H   8192
#define WS_W1_L   16384
#define WS_W2_H   24576
#define WS_W2_L   32768
#define WS_W3_H   40960
#define WS_W3_L   49152
#define WS_WA_H   57344
#define WS_WA_L   73728
#define WS_WF_H   90112
#define WS_WF_L   122880
// total 155648 bytes

__device__ __forceinline__ unsigned short f2bf(float f){
  union { float f; unsigned u; } v; v.f = f;
  unsigned r = v.u + 0x7fffu + ((v.u >> 16) & 1u);
  return (unsigned short)(r >> 16);
}
__device__ __forceinline__ float bf2f(unsigned short h){
  union { unsigned u; float f; } v; v.u = ((unsigned)h) << 16; return v.f;
}
__device__ __forceinline__ void split2(float x, unsigned short& hi, unsigned short& lo){
  hi = f2bf(x);
  lo = f2bf(x - bf2f(hi));   // exact residual
}
__device__ __forceinline__ f32x4 mfma16(const U4& a, const U4& b, f32x4 c){
  return __builtin_amdgcn_mfma_f32_16x16x32_bf16(a.b, b.b, c, 0, 0, 0);
}

// ---- fast RN-bf16 split/pack helpers ----
__device__ __forceinline__ unsigned rnu(unsigned u){
  return u + 0x7fffu + ((u >> 16) & 1u);
}
__device__ __forceinline__ void split_pair(float x0, float x1, unsigned& hi2, unsigned& lo2){
  unsigned r0 = rnu(__float_as_uint(x0)), r1 = rnu(__float_as_uint(x1));
  float l0 = x0 - __uint_as_float(r0 & 0xffff0000u);
  float l1 = x1 - __uint_as_float(r1 & 0xffff0000u);
  hi2 = __builtin_amdgcn_perm(r1, r0, 0x07060302u);
  unsigned s0 = rnu(__float_as_uint(l0)), s1 = rnu(__float_as_uint(l1));
  lo2 = __builtin_amdgcn_perm(s1, s0, 0x07060302u);
}
__device__ __forceinline__ unsigned pack_hl(float z){
  unsigned r = rnu(__float_as_uint(z));
  float lf = z - __uint_as_float(r & 0xffff0000u);
  unsigned s = rnu(__float_as_uint(lf));
  return __builtin_amdgcn_perm(s, r, 0x07060302u);    // low16=hi(z), high16=lo(z)
}

// ------------------------------------------------------------------
// prep kernel: weights -> hi/lo bf16 MFMA B-fragments.
// B-frag: idx = ((ks*NT+nt)*64 + lane)*8 + j ; k = ks*32+(lane>>4)*8+j, n = nt*16+(lane&15)
// ------------------------------------------------------------------
extern "C" __global__ void prep_weights(const float* __restrict__ Wdev,
                                        const float* __restrict__ W1,
                                        const float* __restrict__ W2,
                                        const float* __restrict__ W3,
                                        const float* __restrict__ Wf1,
                                        char* __restrict__ ws)
{
  unsigned short* WdevH = (unsigned short*)(ws + WS_WDEV_H);
  unsigned short* WdevL = (unsigned short*)(ws + WS_WDEV_L);
  unsigned short* WH[3] = {(unsigned short*)(ws+WS_W1_H),(unsigned short*)(ws+WS_W2_H),(unsigned short*)(ws+WS_W3_H)};
  unsigned short* WL[3] = {(unsigned short*)(ws+WS_W1_L),(unsigned short*)(ws+WS_W2_L),(unsigned short*)(ws+WS_W3_L)};
  unsigned short* WaH = (unsigned short*)(ws + WS_WA_H);
  unsigned short* WaL = (unsigned short*)(ws + WS_WA_L);
  unsigned short* WfH = (unsigned short*)(ws + WS_WF_H);
  unsigned short* WfL = (unsigned short*)(ws + WS_WF_L);
  const int total = 2048 + 3*4096 + 8192 + 16384;
  for (int idx = blockIdx.x*256 + threadIdx.x; idx < total; idx += gridDim.x*256){
    if (idx < 2048){                       // Wdev (14x64), K padded to 32, NT=4
      int tt = idx;
      int frag = tt >> 9, within = tt & 511, lane = within >> 3, j = within & 7;
      int nt = frag & 3;
      int k = ((lane>>4)<<3) + j;
      int n = (nt<<4) + (lane & 15);
      float v = (k < 14) ? Wdev[k*64 + n] : 0.f;
      unsigned short h,l; split2(v,h,l); WdevH[tt]=h; WdevL[tt]=l;
    } else if (idx < 2048 + 3*4096){       // W1/W2/W3 (64x64), KS=2, NT=4
      int tt = idx - 2048; int Li = tt / 4096; int r = tt - Li*4096;
      int frag = r >> 9, within = r & 511, lane = within >> 3, j = within & 7;
      int ks = frag >> 2, nt = frag & 3;
      int k = (ks<<5) + ((lane>>4)<<3) + j;
      int n = (nt<<4) + (lane & 15);
      const float* W = (Li==0) ? W1 : ((Li==1) ? W2 : W3);
      float v = W[k*64 + n];
      unsigned short h,l; split2(v,h,l); WH[Li][r]=h; WL[Li][r]=l;
    } else if (idx < 2048 + 3*4096 + 8192){ // Wa = Wf1 rows 0..63 (64x128), KS=2, NT=8
      int r = idx - (2048 + 3*4096);
      int frag = r >> 9, within = r & 511, lane = within >> 3, j = within & 7;
      int ks = frag >> 3, nt = frag & 7;
      int k = (ks<<5) + ((lane>>4)<<3) + j;
      int n = (nt<<4) + (lane & 15);
      float v = Wf1[k*128 + n];
      unsigned short h,l; split2(v,h,l); WaH[r]=h; WaL[r]=l;
    } else {                                // Wfull = Wf1 rows 64..191 (128x128), KS=4, NT=8
      int r = idx - (2048 + 3*4096 + 8192);
      int frag = r >> 9, within = r & 511, lane = within >> 3, j = within & 7;
      int ks = frag >> 3, nt = frag & 7;
      int k = (ks<<5) + ((lane>>4)<<3) + j;
      int n = (nt<<4) + (lane & 15);
      float v = Wf1[(64 + k)*128 + n];
      unsigned short h,l; split2(v,h,l); WfH[r]=h; WfL[r]=l;
    }
  }
}

// ------------------------------------------------------------------
// fused PGCN critic, transposed-first-matmul scheme:
//   MFMA#1 (swapped): Z^T = Y^T @ A^T  -> C-layout has node-in-lane, hidden-in-reg
//   which IS the A-frag orientation for MFMA#2: G = Z' @ W (quad-regroup only).
// Y staged in LDS as [hidden][node] hi/lo bf16 planes, row stride 72 halfwords.
// All LDS ops are b64/b128 with one base reg + immediate offsets.
// launch_bounds(256,6): ~84 reg cap, no spills (R4 lesson).
// ------------------------------------------------------------------
extern "C" __global__ __launch_bounds__(256, 6)
void pgcn_fused(const float* __restrict__ dobs, const float* __restrict__ sobs,
                const float* __restrict__ adj,
                const float* __restrict__ bdev,
                const float* __restrict__ Wsrv, const float* __restrict__ bsrv,
                const float* __restrict__ b1, const float* __restrict__ b2,
                const float* __restrict__ b3,
                const float* __restrict__ bf1, const float* __restrict__ Wf2,
                const float* __restrict__ bf2,
                const char* __restrict__ ws, float* __restrict__ out)
{
  // hi plane: halfwords [0, 4608)  (64 rows x 72), lo plane: [4608, 9216); 18432 B
  __shared__ __align__(16) unsigned short     lds_Yr[9216];
  __shared__ __align__(16) unsigned long long lds_Abits[64];
  __shared__ __align__(16) float    lds_d[64];
  __shared__ __align__(16) float    lds_mp[256];
  __shared__ __align__(16) float    lds_srv[64];
  __shared__ __align__(16) float    lds_s1[128];
  __shared__ __align__(16) unsigned short lds_Vh[128];
  __shared__ __align__(16) unsigned short lds_Vl[128];

  const int t = threadIdx.x;
  const int w = t >> 6;
  const int lane = t & 63;
  const int quad = lane >> 4;
  const int c = lane & 15;
  const long item = blockIdx.x;
  char* Yb = (char*)lds_Yr;

  // ---------- stage adjacency as bitmask: thread t -> row t>>2, 16-col chunk t&3 ----------
  {
    const f32x4* src = (const f32x4*)(adj + item*4096 + ((t>>2)<<6) + ((t&3)<<4));
    unsigned bits = 0;
    for (int i = 0; i < 4; ++i){
      f32x4 v = src[i];
      unsigned b = (v.x != 0.f) | (((unsigned)(v.y != 0.f))<<1)
                 | (((unsigned)(v.z != 0.f))<<2) | (((unsigned)(v.w != 0.f))<<3);
      bits |= b << (i<<2);
    }
    ((unsigned short*)lds_Abits)[t] = (unsigned short)bits;
  }

  // ---------- load device_obs rows as A-operand frags (hi/lo) ----------
  unsigned ahi[4] = {0,0,0,0}, alo[4] = {0,0,0,0};
  {
    int m = (w<<4) + c;
    if (quad < 2 && m < 63){
      const float* rp = dobs + item*882 + m*14 + (quad<<3);
      float e[8];
      f32x2 p0 = *(const f32x2*)(rp);
      f32x2 p1 = *(const f32x2*)(rp+2);
      f32x2 p2 = *(const f32x2*)(rp+4);
      e[0]=p0.x; e[1]=p0.y; e[2]=p1.x; e[3]=p1.y; e[4]=p2.x; e[5]=p2.y;
      if (quad == 0){
        f32x2 p3 = *(const f32x2*)(rp+6);
        e[6]=p3.x; e[7]=p3.y;
      } else {
        e[6]=0.f; e[7]=0.f;                   // k = 14,15 pad
      }
      for (int d0 = 0; d0 < 4; ++d0)
        split_pair(e[2*d0], e[2*d0+1], ahi[d0], alo[d0]);
    }
  }
  __syncthreads();   // [S1] bits ready

  // ---------- degrees from popcount ----------
  if (t < 64){
    unsigned long long mk = lds_Abits[t];
    int deg = __popcll(mk);
    lds_d[t] = 1.0f / sqrtf((float)(deg < 1 ? 1 : deg));
  }
  __syncthreads();   // [S2] d ready

  f32x4 d4v = *(const f32x4*)&lds_d[(w<<4) + (quad<<2)];
  const float dd[4] = {d4v.x, d4v.y, d4v.z, d4v.w};   // d for nodes 16w+4q+r
  const float ddc = lds_d[(w<<4) + c];                // d for node 16w+c

  // ---------- B-frag of A^T from bitmask (binary exact, held in regs) ----------
  // At[k=32ks+8q+j][n=16w+c] = A[16w+c][32ks+8q+j]
  U4 atk[2];
  {
    unsigned long long mk = lds_Abits[(w<<4) + c];
    for (int ks = 0; ks < 2; ++ks){
      unsigned byt = (unsigned)(mk >> ((ks<<5) + (quad<<3))) & 0xffu;
      for (int r = 0; r < 4; ++r){
        unsigned e = 0u - ((byt >> (2*r)) & 1u);
        unsigned o = 0u - ((byt >> (2*r+1)) & 1u);
        atk[ks].u[r] = (e & 0x3f80u) | (o & 0x3f800000u);
      }
    }
  }

  // LDS base offsets (bytes); all subsequent accesses use immediate offsets
  const int ybw = (c*72 + (w<<4) + (quad<<2)) << 1;          // Y write: row 16nt+c, col 16w+4q  (+2304*nt)
  const int yrd = (c*72 + (quad<<3)) << 1;                    // Y read : row 16mt+c, col 8q      (+2304*mt+64*ks)
  const int zbw = (((w<<4)+c)*72 + (quad<<2)) << 1;           // Z write: row 16w+c,  col 16mt+4q (+32*mt)
  const int zrd = (((w<<4)+c)*72 + (quad<<3)) << 1;           // Z read : row 16w+c,  col 8q      (+64*ks)

  float hcur[4][4];

  // ---------- embed: x = relu(dobs@Wdev + bdev); row63 = server; write Y1 = d*x ----------
  {
    U4 a_h, a_l;
    a_h.u = uint4v{ahi[0],ahi[1],ahi[2],ahi[3]};
    a_l.u = uint4v{alo[0],alo[1],alo[2],alo[3]};
    const uint4v* WdH = (const uint4v*)(ws + WS_WDEV_H);
    const uint4v* WdL = (const uint4v*)(ws + WS_WDEV_L);
    float srvv4[4];
    if (w == 3 && quad == 3){
      float s0 = sobs[item*3+0], s1v = sobs[item*3+1], s2v = sobs[item*3+2];
      for (int nt = 0; nt < 4; ++nt){
        int col = c + (nt<<4);
        float v = s0*Wsrv[col] + s1v*Wsrv[64+col] + s2v*Wsrv[128+col] + bsrv[col];
        srvv4[nt] = fmaxf(v, 0.f);
      }
    }
    for (int nt = 0; nt < 4; ++nt){
      U4 wh, wl;
      wh.u = WdH[(nt<<6) + lane];
      wl.u = WdL[(nt<<6) + lane];
      f32x4 g = {0.f,0.f,0.f,0.f};
      g = mfma16(a_h, wh, g);
      g = mfma16(a_h, wl, g);
      g = mfma16(a_l, wh, g);
      float bb = bdev[c + (nt<<4)];
      float y[4];
      for (int r = 0; r < 4; ++r) y[r] = fmaxf(g[r] + bb, 0.f);
      if (w == 3 && quad == 3) y[3] = srvv4[nt];    // node 63 = server embedding
      for (int r = 0; r < 4; ++r) y[r] *= dd[r];    // Y = d * x
      unsigned h01, l01, h23, l23;
      split_pair(y[0], y[1], h01, l01);
      split_pair(y[2], y[3], h23, l23);
      *(uint2v*)(Yb + ybw + 2304*nt)        = uint2v{ h01, h23 };   // hi plane
      *(uint2v*)(Yb + ybw + 2304*nt + 9216) = uint2v{ l01, l23 };   // lo plane
    }
  }
  __syncthreads();   // Y1 ready

  // ---------- 3 GCN layers ----------
  const uint4v* WH_tab[3] = {(const uint4v*)(ws+WS_W1_H),(const uint4v*)(ws+WS_W2_H),(const uint4v*)(ws+WS_W3_H)};
  const uint4v* WL_tab[3] = {(const uint4v*)(ws+WS_W1_L),(const uint4v*)(ws+WS_W2_L),(const uint4v*)(ws+WS_W3_L)};
  const float* bias_tab[3] = {b1, b2, b3};

  for (int L = 0; L < 3; ++L){
    // step 1 (swapped): Zt = Yt @ At ; zacc[mt] = Zt[hidden 16mt+4q+r][node 16w+c]
    f32x4 zacc[4];
    for (int mt = 0; mt < 4; ++mt){
      f32x4 g = {0.f,0.f,0.f,0.f};
      for (int ks = 0; ks < 2; ++ks){
        U4 yh, yl;
        yh.u = *(const uint4v*)(Yb + yrd + 2304*mt + 64*ks);
        yl.u = *(const uint4v*)(Yb + yrd + 2304*mt + 64*ks + 9216);
        g = mfma16(yh, atk[ks], g);
        g = mfma16(yl, atk[ks], g);
      }
      zacc[mt] = g;
    }
    __syncthreads();  // [B2] all Y reads done; region reusable

    // step 2: Z' = d*Zt, regroup into per-wave slice rows [16w+c][hidden] (planes)
    for (int mt = 0; mt < 4; ++mt){
      unsigned h01, l01, h23, l23;
      split_pair(zacc[mt][0]*ddc, zacc[mt][1]*ddc, h01, l01);
      split_pair(zacc[mt][2]*ddc, zacc[mt][3]*ddc, h23, l23);
      *(uint2v*)(Yb + zbw + 32*mt)        = uint2v{ h01, h23 };
      *(uint2v*)(Yb + zbw + 32*mt + 9216) = uint2v{ l01, l23 };
    }
    __threadfence_block();   // wave-private rows: order writes before reads
    U4 zh[2], zl[2];
    for (int ks = 0; ks < 2; ++ks){
      zh[ks].u = *(const uint4v*)(Yb + zrd + 64*ks);
      zl[ks].u = *(const uint4v*)(Yb + zrd + 64*ks + 9216);
    }

    // step 3: G = Z' @ W (3-pass split), h = relu(G + b); node in reg, hidden in lane
    const uint4v* WHp = WH_tab[L];
    const uint4v* WLp = WL_tab[L];
    const float* bp = bias_tab[L];
    for (int nt = 0; nt < 4; ++nt){
      f32x4 g = {0.f,0.f,0.f,0.f};
      for (int ks = 0; ks < 2; ++ks){
        U4 wh, wl;
        wh.u = WHp[((ks<<2)+nt)*64 + lane];
        wl.u = WLp[((ks<<2)+nt)*64 + lane];
        g = mfma16(zh[ks], wh, g);
        g = mfma16(zh[ks], wl, g);
        g = mfma16(zl[ks], wh, g);
      }
      float bb = bp[c + (nt<<4)];
      for (int r = 0; r < 4; ++r) hcur[nt][r] = fmaxf(g[r] + bb, 0.f);
    }
    __syncthreads();  // [B3] all Z' reads done; region reusable

    if (L < 2){
      // step 4: write next Y = d * h into [hidden][node] planes
      for (int nt = 0; nt < 4; ++nt){
        unsigned h01, l01, h23, l23;
        split_pair(hcur[nt][0]*dd[0], hcur[nt][1]*dd[1], h01, l01);
        split_pair(hcur[nt][2]*dd[2], hcur[nt][3]*dd[3], h23, l23);
        *(uint2v*)(Yb + ybw + 2304*nt)        = uint2v{ h01, h23 };
        *(uint2v*)(Yb + ybw + 2304*nt + 9216) = uint2v{ l01, l23 };
      }
      __syncthreads();  // next layer's Y ready
    }
  }

  // ---------- head ----------
  unsigned* zbuf = (unsigned*)Yb + (w<<10);          // per-wave 4 KB pi-swizzle slice (region free after [B3])
  const int piL = (lane>>2) | ((lane&3)<<4);
  const int s0L = (piL>>2) & 1;

  // col-sum partials (quad-reduced in-wave) + server row
  {
    bool isSrvLane = (w == 3) && (quad == 3);
    float cs[4];
    for (int nt = 0; nt < 4; ++nt){
      float s = hcur[nt][0] + hcur[nt][1] + hcur[nt][2] + hcur[nt][3];
      if (isSrvLane){ s -= hcur[nt][3]; lds_srv[c + (nt<<4)] = hcur[nt][3]; }
      s += __shfl_xor(s, 16);
      s += __shfl_xor(s, 32);
      cs[nt] = s;
    }
    if (quad == 0)
      for (int nt = 0; nt < 4; ++nt) lds_mp[(w<<6) + c + (nt<<4)] = cs[nt];
  }
  // transpose h -> A-frags via pi-swizzled per-wave slice
  for (int nt = 0; nt < 4; ++nt){
    int ks = nt >> 1;
    int lcBase = (quad<<2) + ((((nt&1)<<1) + (c>>3)) << 4);
    int e = c & 7;
    for (int r = 0; r < 4; ++r){
      unsigned pk = pack_hl(hcur[nt][r]);
      int lane_c = lcBase + r;
      int pi = (lane_c>>2) | ((lane_c&3)<<4);
      int sel = ((e>>2) ^ (pi>>2)) & 1;
      zbuf[(ks<<9) + (pi<<3) + (sel<<2) + (e&3)] = pk;
    }
  }
  __syncthreads();  // [Bh1] partials + srv + zbuf writes done

  // V = [mean(63 dev rows); srv] split to bf16 hi/lo in LDS
  if (t < 64){
    float mv = (lds_mp[t] + lds_mp[64+t] + lds_mp[128+t] + lds_mp[192+t]) * (1.0f/63.0f);
    unsigned short h,l; split2(mv,h,l);
    lds_Vh[t]=h; lds_Vl[t]=l;
  } else if (t < 128){
    float sv = lds_srv[t-64];
    unsigned short h,l; split2(sv,h,l);
    lds_Vh[t]=h; lds_Vl[t]=l;
  }
  __syncthreads();  // [Bh2] V ready; zbuf reads safe (2 barriers after writes)

  // read back h A-frags
  U4 hh[2], hl[2];
  for (int ks = 0; ks < 2; ++ks){
    uint4v qa = *(const uint4v*)&zbuf[(ks<<9) + (piL<<3) + (s0L<<2)];
    uint4v qb = *(const uint4v*)&zbuf[(ks<<9) + (piL<<3) + ((1-s0L)<<2)];
    hh[ks].u = uint4v{ (qa.y<<16)|(qa.x&0xffffu), (qa.w<<16)|(qa.z&0xffffu),
                       (qb.y<<16)|(qb.x&0xffffu), (qb.w<<16)|(qb.z&0xffffu) };
    hl[ks].u = uint4v{ (qa.y&0xffff0000u)|(qa.x>>16), (qa.w&0xffff0000u)|(qa.z>>16),
                       (qb.y&0xffff0000u)|(qb.x>>16), (qb.w&0xffff0000u)|(qb.z>>16) };
  }

  // s1 = V @ Wfull + bf1 via MFMA (row 0 only); wave w owns cols 32w..32w+31
  {
    const uint4v* WfH = (const uint4v*)(ws + WS_WF_H);
    const uint4v* WfL = (const uint4v*)(ws + WS_WF_L);
    f32x4 sacc0 = {0.f,0.f,0.f,0.f}, sacc1 = {0.f,0.f,0.f,0.f};
    for (int ks = 0; ks < 4; ++ks){
      U4 vh, vl;
      vh.u = *(const uint4v*)((const char*)lds_Vh + (ks<<6) + (quad<<4));
      vl.u = *(const uint4v*)((const char*)lds_Vl + (ks<<6) + (quad<<4));
      if (c != 0){ vh.u = uint4v{0,0,0,0}; vl.u = uint4v{0,0,0,0}; }
      int nt0 = (w<<1);
      U4 wh, wl;
      wh.u = WfH[((ks<<3)+nt0)*64 + lane];
      wl.u = WfL[((ks<<3)+nt0)*64 + lane];
      sacc0 = mfma16(vh, wh, sacc0);
      sacc0 = mfma16(vh, wl, sacc0);
      sacc0 = mfma16(vl, wh, sacc0);
      wh.u = WfH[((ks<<3)+nt0+1)*64 + lane];
      wl.u = WfL[((ks<<3)+nt0+1)*64 + lane];
      sacc1 = mfma16(vh, wh, sacc1);
      sacc1 = mfma16(vh, wl, sacc1);
      sacc1 = mfma16(vl, wh, sacc1);
    }
    if (quad == 0){
      int col0 = c + (w<<5);
      lds_s1[col0]      = sacc0[0] + bf1[col0];
      lds_s1[col0 + 16] = sacc1[0] + bf1[col0 + 16];
    }
  }
  __syncthreads();  // [Bh3] s1 ready

  // P = h @ Wa (3-pass split), epilogue: out_n = sum_j relu(P+s1)[j]*Wf2[j]
  const uint4v* WaH = (const uint4v*)(ws + WS_WA_H);
  const uint4v* WaL = (const uint4v*)(ws + WS_WA_L);
  float outacc[4] = {0.f,0.f,0.f,0.f};
  for (int nt = 0; nt < 8; ++nt){
    f32x4 g = {0.f,0.f,0.f,0.f};
    for (int ks = 0; ks < 2; ++ks){
      U4 wh, wl;
      wh.u = WaH[((ks<<3)+nt)*64 + lane];
      wl.u = WaL[((ks<<3)+nt)*64 + lane];
      g = mfma16(hh[ks], wh, g);
      g = mfma16(hh[ks], wl, g);
      g = mfma16(hl[ks], wh, g);
    }
    int col = c + (nt<<4);
    float sv = lds_s1[col];
    float w2 = Wf2[col];
    for (int r = 0; r < 4; ++r){
      float zz = fmaxf(g[r] + sv, 0.f);
      outacc[r] += zz * w2;
    }
  }
  {
    float bb = bf2[0];
    for (int r = 0; r < 4; ++r){
      float v = outacc[r];
      v += __shfl_xor(v, 1); v += __shfl_xor(v, 2);
      v += __shfl_xor(v, 4); v += __shfl_xor(v, 8);
      if (c == 0){
        int row = (w<<4) + (quad<<2) + r;
        if (row < 63) out[item*63 + row] = v + bb;
      }
    }
  }
}

extern "C" void kernel_launch(void* const* d_in, const int* in_sizes, int n_in,
                              void* d_out, int out_size, void* d_ws, size_t ws_size,
                              hipStream_t stream)
{
  const float* dobs = (const float*)d_in[0];
  const float* sobs = (const float*)d_in[1];
  const float* adj  = (const float*)d_in[2];
  const float* Wdev = (const float*)d_in[3];
  const float* bdev = (const float*)d_in[4];
  const float* Wsrv = (const float*)d_in[5];
  const float* bsrv = (const float*)d_in[6];
  const float* W1   = (const float*)d_in[7];
  const float* b1   = (const float*)d_in[8];
  const float* W2   = (const float*)d_in[9];
  const float* b2   = (const float*)d_in[10];
  const float* W3   = (const float*)d_in[11];
  const float* b3   = (const float*)d_in[12];
  const float* Wf1  = (const float*)d_in[13];
  const float* bf1  = (const float*)d_in[14];
  const float* Wf2  = (const float*)d_in[15];
  const float* bf2  = (const float*)d_in[16];
  float* out = (float*)d_out;
  char* ws = (char*)d_ws;
  int nb = in_sizes[1] / 3;   // batch size (server_obs is B x 3)

  prep_weights<<<dim3(160), dim3(256), 0, stream>>>(Wdev, W1, W2, W3, Wf1, ws);
  pgcn_fused<<<dim3(nb), dim3(256), 0, stream>>>(dobs, sobs, adj, bdev, Wsrv, bsrv,
                                                 b1, b2, b3, bf1, Wf2, bf2, ws, out);
}

// Round 7
// 624.831 us; speedup vs baseline: 1.2681x; 1.0086x over previous
//
#include <hip/hip_runtime.h>
#include <hip/hip_bf16.h>
#include <stdint.h>

typedef __attribute__((ext_vector_type(8))) __bf16 bf16x8;
typedef __attribute__((ext_vector_type(4))) float f32x4;
typedef __attribute__((ext_vector_type(2))) float f32x2;
typedef __attribute__((ext_vector_type(4))) unsigned uint4v;
typedef __attribute__((ext_vector_type(2))) unsigned uint2v;

union U4 { uint4v u; bf16x8 b; };

// ---- d_ws layout (bytes) ----
#define WS_WDEV_H 0
#define WS_WDEV_L 4096
#define WS_W1_H   8192
#define WS_W1_L   16384
#define WS_W2_H   24576
#define WS_W2_L   32768
#define WS_W3_H   40960
#define WS_W3_L   49152
#define WS_WA_H   57344
#define WS_WA_L   73728
#define WS_WF_H   90112
#define WS_WF_L   122880
// total 155648 bytes

__device__ __forceinline__ unsigned short f2bf(float f){
  union { float f; unsigned u; } v; v.f = f;
  unsigned r = v.u + 0x7fffu + ((v.u >> 16) & 1u);
  return (unsigned short)(r >> 16);
}
__device__ __forceinline__ float bf2f(unsigned short h){
  union { unsigned u; float f; } v; v.u = ((unsigned)h) << 16; return v.f;
}
__device__ __forceinline__ void split2(float x, unsigned short& hi, unsigned short& lo){
  hi = f2bf(x);
  lo = f2bf(x - bf2f(hi));   // exact residual
}
__device__ __forceinline__ f32x4 mfma16(const U4& a, const U4& b, f32x4 c){
  return __builtin_amdgcn_mfma_f32_16x16x32_bf16(a.b, b.b, c, 0, 0, 0);
}

// ---- HW packed bf16 conversion (v_cvt_pk_bf16_f32, RNE — bit-identical to rnu) ----
__device__ __forceinline__ unsigned cvt_pk_bf(float a, float b){
  float2 p; p.x = a; p.y = b;
  union { __hip_bfloat162 h; unsigned u; } cv;
  cv.h = __float22bfloat162_rn(p);          // low16 = bf(a), high16 = bf(b)
  return cv.u;
}
// hi2 = (bf16(x1)<<16)|bf16(x0), lo2 = same for RN residuals
__device__ __forceinline__ void split_pair(float x0, float x1, unsigned& hi2, unsigned& lo2){
  hi2 = cvt_pk_bf(x0, x1);
  lo2 = cvt_pk_bf(x0 - __uint_as_float(hi2 << 16),
                  x1 - __uint_as_float(hi2 & 0xffff0000u));
}
// (lo16<<16)|hi16 for one value (head zbuf element format)
__device__ __forceinline__ unsigned pack_hl(float z){
  unsigned h = cvt_pk_bf(z, 0.f) & 0xffffu;
  float r = z - __uint_as_float(h << 16);
  return (cvt_pk_bf(0.f, r) & 0xffff0000u) | h;
}

// ------------------------------------------------------------------
// prep kernel: weights -> hi/lo bf16 MFMA B-fragments.
// B-frag: idx = ((ks*NT+nt)*64 + lane)*8 + j ; k = ks*32+(lane>>4)*8+j, n = nt*16+(lane&15)
// ------------------------------------------------------------------
extern "C" __global__ void prep_weights(const float* __restrict__ Wdev,
                                        const float* __restrict__ W1,
                                        const float* __restrict__ W2,
                                        const float* __restrict__ W3,
                                        const float* __restrict__ Wf1,
                                        char* __restrict__ ws)
{
  unsigned short* WdevH = (unsigned short*)(ws + WS_WDEV_H);
  unsigned short* WdevL = (unsigned short*)(ws + WS_WDEV_L);
  unsigned short* WH[3] = {(unsigned short*)(ws+WS_W1_H),(unsigned short*)(ws+WS_W2_H),(unsigned short*)(ws+WS_W3_H)};
  unsigned short* WL[3] = {(unsigned short*)(ws+WS_W1_L),(unsigned short*)(ws+WS_W2_L),(unsigned short*)(ws+WS_W3_L)};
  unsigned short* WaH = (unsigned short*)(ws + WS_WA_H);
  unsigned short* WaL = (unsigned short*)(ws + WS_WA_L);
  unsigned short* WfH = (unsigned short*)(ws + WS_WF_H);
  unsigned short* WfL = (unsigned short*)(ws + WS_WF_L);
  const int total = 2048 + 3*4096 + 8192 + 16384;
  for (int idx = blockIdx.x*256 + threadIdx.x; idx < total; idx += gridDim.x*256){
    if (idx < 2048){                       // Wdev (14x64), K padded to 32, NT=4
      int tt = idx;
      int frag = tt >> 9, within = tt & 511, lane = within >> 3, j = within & 7;
      int nt = frag & 3;
      int k = ((lane>>4)<<3) + j;
      int n = (nt<<4) + (lane & 15);
      float v = (k < 14) ? Wdev[k*64 + n] : 0.f;
      unsigned short h,l; split2(v,h,l); WdevH[tt]=h; WdevL[tt]=l;
    } else if (idx < 2048 + 3*4096){       // W1/W2/W3 (64x64), KS=2, NT=4
      int tt = idx - 2048; int Li = tt / 4096; int r = tt - Li*4096;
      int frag = r >> 9, within = r & 511, lane = within >> 3, j = within & 7;
      int ks = frag >> 2, nt = frag & 3;
      int k = (ks<<5) + ((lane>>4)<<3) + j;
      int n = (nt<<4) + (lane & 15);
      const float* W = (Li==0) ? W1 : ((Li==1) ? W2 : W3);
      float v = W[k*64 + n];
      unsigned short h,l; split2(v,h,l); WH[Li][r]=h; WL[Li][r]=l;
    } else if (idx < 2048 + 3*4096 + 8192){ // Wa = Wf1 rows 0..63 (64x128), KS=2, NT=8
      int r = idx - (2048 + 3*4096);
      int frag = r >> 9, within = r & 511, lane = within >> 3, j = within & 7;
      int ks = frag >> 3, nt = frag & 7;
      int k = (ks<<5) + ((lane>>4)<<3) + j;
      int n = (nt<<4) + (lane & 15);
      float v = Wf1[k*128 + n];
      unsigned short h,l; split2(v,h,l); WaH[r]=h; WaL[r]=l;
    } else {                                // Wfull = Wf1 rows 64..191 (128x128), KS=4, NT=8
      int r = idx - (2048 + 3*4096 + 8192);
      int frag = r >> 9, within = r & 511, lane = within >> 3, j = within & 7;
      int ks = frag >> 3, nt = frag & 7;
      int k = (ks<<5) + ((lane>>4)<<3) + j;
      int n = (nt<<4) + (lane & 15);
      float v = Wf1[(64 + k)*128 + n];
      unsigned short h,l; split2(v,h,l); WfH[r]=h; WfL[r]=l;
    }
  }
}

// ------------------------------------------------------------------
// fused PGCN critic, transposed-first-matmul scheme (R6 structure):
//   MFMA#1 (swapped): Z^T = Y^T @ A^T  -> node-in-lane, hidden-in-reg C-layout
//   = A-frag orientation for MFMA#2: G = Z' @ W (quad-regroup via LDS planes).
// launch_bounds(256,6): ~84 unified regs/wave, no spills (R4 lesson).
// ------------------------------------------------------------------
extern "C" __global__ __launch_bounds__(256, 6)
void pgcn_fused(const float* __restrict__ dobs, const float* __restrict__ sobs,
                const float* __restrict__ adj,
                const float* __restrict__ bdev,
                const float* __restrict__ Wsrv, const float* __restrict__ bsrv,
                const float* __restrict__ b1, const float* __restrict__ b2,
                const float* __restrict__ b3,
                const float* __restrict__ bf1, const float* __restrict__ Wf2,
                const float* __restrict__ bf2,
                const char* __restrict__ ws, float* __restrict__ out)
{
  // hi plane: halfwords [0, 4608)  (64 rows x 72), lo plane: [4608, 9216); 18432 B
  __shared__ __align__(16) unsigned short     lds_Yr[9216];
  __shared__ __align__(16) unsigned long long lds_Abits[64];
  __shared__ __align__(16) float    lds_d[64];
  __shared__ __align__(16) float    lds_mp[256];
  __shared__ __align__(16) float    lds_srv[64];
  __shared__ __align__(16) float    lds_s1[128];
  __shared__ __align__(16) unsigned short lds_Vh[128];
  __shared__ __align__(16) unsigned short lds_Vl[128];

  const int t = threadIdx.x;
  const int w = t >> 6;
  const int lane = t & 63;
  const int quad = lane >> 4;
  const int c = lane & 15;
  const long item = blockIdx.x;
  char* Yb = (char*)lds_Yr;

  // ---------- stage adjacency as bitmask: thread t -> row t>>2, 16-col chunk t&3 ----------
  {
    const f32x4* src = (const f32x4*)(adj + item*4096 + ((t>>2)<<6) + ((t&3)<<4));
    unsigned bits = 0;
    for (int i = 0; i < 4; ++i){
      f32x4 v = src[i];
      unsigned b = (v.x != 0.f) | (((unsigned)(v.y != 0.f))<<1)
                 | (((unsigned)(v.z != 0.f))<<2) | (((unsigned)(v.w != 0.f))<<3);
      bits |= b << (i<<2);
    }
    ((unsigned short*)lds_Abits)[t] = (unsigned short)bits;
  }

  // ---------- load device_obs rows as A-operand frags (hi/lo) ----------
  unsigned ahi[4] = {0,0,0,0}, alo[4] = {0,0,0,0};
  {
    int m = (w<<4) + c;
    if (quad < 2 && m < 63){
      const float* rp = dobs + item*882 + m*14 + (quad<<3);
      float e[8];
      f32x2 p0 = *(const f32x2*)(rp);
      f32x2 p1 = *(const f32x2*)(rp+2);
      f32x2 p2 = *(const f32x2*)(rp+4);
      e[0]=p0.x; e[1]=p0.y; e[2]=p1.x; e[3]=p1.y; e[4]=p2.x; e[5]=p2.y;
      if (quad == 0){
        f32x2 p3 = *(const f32x2*)(rp+6);
        e[6]=p3.x; e[7]=p3.y;
      } else {
        e[6]=0.f; e[7]=0.f;                   // k = 14,15 pad
      }
      for (int d0 = 0; d0 < 4; ++d0)
        split_pair(e[2*d0], e[2*d0+1], ahi[d0], alo[d0]);
    }
  }
  __syncthreads();   // [S1] bits ready

  // ---------- degrees from popcount ----------
  if (t < 64){
    unsigned long long mk = lds_Abits[t];
    int deg = __popcll(mk);
    lds_d[t] = 1.0f / sqrtf((float)(deg < 1 ? 1 : deg));
  }
  __syncthreads();   // [S2] d ready

  f32x4 d4v = *(const f32x4*)&lds_d[(w<<4) + (quad<<2)];
  const float dd[4] = {d4v.x, d4v.y, d4v.z, d4v.w};   // d for nodes 16w+4q+r
  const float ddc = lds_d[(w<<4) + c];                // d for node 16w+c

  // ---------- B-frag of A^T from bitmask (binary exact, held in regs) ----------
  U4 atk[2];
  {
    unsigned long long mk = lds_Abits[(w<<4) + c];
    for (int ks = 0; ks < 2; ++ks){
      unsigned byt = (unsigned)(mk >> ((ks<<5) + (quad<<3))) & 0xffu;
      for (int r = 0; r < 4; ++r){
        unsigned e = 0u - ((byt >> (2*r)) & 1u);
        unsigned o = 0u - ((byt >> (2*r+1)) & 1u);
        atk[ks].u[r] = (e & 0x3f80u) | (o & 0x3f800000u);
      }
    }
  }

  // LDS base offsets (bytes)
  const int ybw = (c*72 + (w<<4) + (quad<<2)) << 1;          // Y write (+2304*nt)
  const int yrd = (c*72 + (quad<<3)) << 1;                    // Y read  (+2304*mt+64*ks)
  const int zbw = (((w<<4)+c)*72 + (quad<<2)) << 1;           // Z write (+32*mt)
  const int zrd = (((w<<4)+c)*72 + (quad<<3)) << 1;           // Z read  (+64*ks)

  float hcur[4][4];

  // ---------- embed: x = relu(dobs@Wdev + bdev); row63 = server; write Y1 = d*x ----------
  {
    U4 a_h, a_l;
    a_h.u = uint4v{ahi[0],ahi[1],ahi[2],ahi[3]};
    a_l.u = uint4v{alo[0],alo[1],alo[2],alo[3]};
    const uint4v* WdH = (const uint4v*)(ws + WS_WDEV_H);
    const uint4v* WdL = (const uint4v*)(ws + WS_WDEV_L);
    float srvv4[4];
    if (w == 3 && quad == 3){
      float s0 = sobs[item*3+0], s1v = sobs[item*3+1], s2v = sobs[item*3+2];
      for (int nt = 0; nt < 4; ++nt){
        int col = c + (nt<<4);
        float v = s0*Wsrv[col] + s1v*Wsrv[64+col] + s2v*Wsrv[128+col] + bsrv[col];
        srvv4[nt] = fmaxf(v, 0.f);
      }
    }
    for (int nt = 0; nt < 4; ++nt){
      U4 wh, wl;
      wh.u = WdH[(nt<<6) + lane];
      wl.u = WdL[(nt<<6) + lane];
      f32x4 g = {0.f,0.f,0.f,0.f};
      g = mfma16(a_h, wh, g);
      g = mfma16(a_h, wl, g);
      g = mfma16(a_l, wh, g);
      float bb = bdev[c + (nt<<4)];
      float y[4];
      for (int r = 0; r < 4; ++r) y[r] = fmaxf(g[r] + bb, 0.f);
      if (w == 3 && quad == 3) y[3] = srvv4[nt];    // node 63 = server embedding
      for (int r = 0; r < 4; ++r) y[r] *= dd[r];    // Y = d * x
      unsigned h01, l01, h23, l23;
      split_pair(y[0], y[1], h01, l01);
      split_pair(y[2], y[3], h23, l23);
      *(uint2v*)(Yb + ybw + 2304*nt)        = uint2v{ h01, h23 };   // hi plane
      *(uint2v*)(Yb + ybw + 2304*nt + 9216) = uint2v{ l01, l23 };   // lo plane
    }
  }
  __syncthreads();   // Y1 ready

  // ---------- 3 GCN layers ----------
  const uint4v* WH_tab[3] = {(const uint4v*)(ws+WS_W1_H),(const uint4v*)(ws+WS_W2_H),(const uint4v*)(ws+WS_W3_H)};
  const uint4v* WL_tab[3] = {(const uint4v*)(ws+WS_W1_L),(const uint4v*)(ws+WS_W2_L),(const uint4v*)(ws+WS_W3_L)};
  const float* bias_tab[3] = {b1, b2, b3};

  for (int L = 0; L < 3; ++L){
    // step 1 (swapped): Zt = Yt @ At
    f32x4 zacc[4];
    for (int mt = 0; mt < 4; ++mt){
      f32x4 g = {0.f,0.f,0.f,0.f};
      for (int ks = 0; ks < 2; ++ks){
        U4 yh, yl;
        yh.u = *(const uint4v*)(Yb + yrd + 2304*mt + 64*ks);
        yl.u = *(const uint4v*)(Yb + yrd + 2304*mt + 64*ks + 9216);
        g = mfma16(yh, atk[ks], g);
        g = mfma16(yl, atk[ks], g);
      }
      zacc[mt] = g;
    }
    __syncthreads();  // [B2] all Y reads done; region reusable

    // step 2: Z' = d*Zt, regroup into per-wave rows [16w+c][hidden] (planes)
    for (int mt = 0; mt < 4; ++mt){
      unsigned h01, l01, h23, l23;
      split_pair(zacc[mt][0]*ddc, zacc[mt][1]*ddc, h01, l01);
      split_pair(zacc[mt][2]*ddc, zacc[mt][3]*ddc, h23, l23);
      *(uint2v*)(Yb + zbw + 32*mt)        = uint2v{ h01, h23 };
      *(uint2v*)(Yb + zbw + 32*mt + 9216) = uint2v{ l01, l23 };
    }
    __threadfence_block();   // wave-private rows: order writes before reads
    U4 zh[2], zl[2];
    for (int ks = 0; ks < 2; ++ks){
      zh[ks].u = *(const uint4v*)(Yb + zrd + 64*ks);
      zl[ks].u = *(const uint4v*)(Yb + zrd + 64*ks + 9216);
    }

    // step 3: G = Z' @ W (3-pass split), h = relu(G + b)
    const uint4v* WHp = WH_tab[L];
    const uint4v* WLp = WL_tab[L];
    const float* bp = bias_tab[L];
    for (int nt = 0; nt < 4; ++nt){
      f32x4 g = {0.f,0.f,0.f,0.f};
      for (int ks = 0; ks < 2; ++ks){
        U4 wh, wl;
        wh.u = WHp[((ks<<2)+nt)*64 + lane];
        wl.u = WLp[((ks<<2)+nt)*64 + lane];
        g = mfma16(zh[ks], wh, g);
        g = mfma16(zh[ks], wl, g);
        g = mfma16(zl[ks], wh, g);
      }
      float bb = bp[c + (nt<<4)];
      for (int r = 0; r < 4; ++r) hcur[nt][r] = fmaxf(g[r] + bb, 0.f);
    }
    __syncthreads();  // [B3] all Z' reads done; region reusable

    if (L < 2){
      // step 4: write next Y = d * h into [hidden][node] planes
      for (int nt = 0; nt < 4; ++nt){
        unsigned h01, l01, h23, l23;
        split_pair(hcur[nt][0]*dd[0], hcur[nt][1]*dd[1], h01, l01);
        split_pair(hcur[nt][2]*dd[2], hcur[nt][3]*dd[3], h23, l23);
        *(uint2v*)(Yb + ybw + 2304*nt)        = uint2v{ h01, h23 };
        *(uint2v*)(Yb + ybw + 2304*nt + 9216) = uint2v{ l01, l23 };
      }
      __syncthreads();  // next layer's Y ready
    }
  }

  // ---------- head ----------
  unsigned* zbuf = (unsigned*)Yb + (w<<10);          // per-wave 4 KB pi-swizzle slice
  const int piL = (lane>>2) | ((lane&3)<<4);
  const int s0L = (piL>>2) & 1;

  // col-sum partials (quad-reduced in-wave) + server row
  {
    bool isSrvLane = (w == 3) && (quad == 3);
    float cs[4];
    for (int nt = 0; nt < 4; ++nt){
      float s = hcur[nt][0] + hcur[nt][1] + hcur[nt][2] + hcur[nt][3];
      if (isSrvLane){ s -= hcur[nt][3]; lds_srv[c + (nt<<4)] = hcur[nt][3]; }
      s += __shfl_xor(s, 16);
      s += __shfl_xor(s, 32);
      cs[nt] = s;
    }
    if (quad == 0)
      for (int nt = 0; nt < 4; ++nt) lds_mp[(w<<6) + c + (nt<<4)] = cs[nt];
  }
  // transpose h -> A-frags via pi-swizzled per-wave slice
  for (int nt = 0; nt < 4; ++nt){
    int ks = nt >> 1;
    int lcBase = (quad<<2) + ((((nt&1)<<1) + (c>>3)) << 4);
    int e = c & 7;
    for (int r = 0; r < 4; ++r){
      unsigned pk = pack_hl(hcur[nt][r]);
      int lane_c = lcBase + r;
      int pi = (lane_c>>2) | ((lane_c&3)<<4);
      int sel = ((e>>2) ^ (pi>>2)) & 1;
      zbuf[(ks<<9) + (pi<<3) + (sel<<2) + (e&3)] = pk;
    }
  }
  __syncthreads();  // [Bh1] partials + srv + zbuf writes done

  // V = [mean(63 dev rows); srv] split to bf16 hi/lo in LDS
  if (t < 64){
    float mv = (lds_mp[t] + lds_mp[64+t] + lds_mp[128+t] + lds_mp[192+t]) * (1.0f/63.0f);
    unsigned short h,l; split2(mv,h,l);
    lds_Vh[t]=h; lds_Vl[t]=l;
  } else if (t < 128){
    float sv = lds_srv[t-64];
    unsigned short h,l; split2(sv,h,l);
    lds_Vh[t]=h; lds_Vl[t]=l;
  }
  __syncthreads();  // [Bh2] V ready; zbuf reads safe

  // read back h A-frags
  U4 hh[2], hl[2];
  for (int ks = 0; ks < 2; ++ks){
    uint4v qa = *(const uint4v*)&zbuf[(ks<<9) + (piL<<3) + (s0L<<2)];
    uint4v qb = *(const uint4v*)&zbuf[(ks<<9) + (piL<<3) + ((1-s0L)<<2)];
    hh[ks].u = uint4v{ (qa.y<<16)|(qa.x&0xffffu), (qa.w<<16)|(qa.z&0xffffu),
                       (qb.y<<16)|(qb.x&0xffffu), (qb.w<<16)|(qb.z&0xffffu) };
    hl[ks].u = uint4v{ (qa.y&0xffff0000u)|(qa.x>>16), (qa.w&0xffff0000u)|(qa.z>>16),
                       (qb.y&0xffff0000u)|(qb.x>>16), (qb.w&0xffff0000u)|(qb.z>>16) };
  }

  // s1 = V @ Wfull + bf1 via MFMA (row 0 only); wave w owns cols 32w..32w+31
  {
    const uint4v* WfH = (const uint4v*)(ws + WS_WF_H);
    const uint4v* WfL = (const uint4v*)(ws + WS_WF_L);
    f32x4 sacc0 = {0.f,0.f,0.f,0.f}, sacc1 = {0.f,0.f,0.f,0.f};
    for (int ks = 0; ks < 4; ++ks){
      U4 vh, vl;
      vh.u = *(const uint4v*)((const char*)lds_Vh + (ks<<6) + (quad<<4));
      vl.u = *(const uint4v*)((const char*)lds_Vl + (ks<<6) + (quad<<4));
      if (c != 0){ vh.u = uint4v{0,0,0,0}; vl.u = uint4v{0,0,0,0}; }
      int nt0 = (w<<1);
      U4 wh, wl;
      wh.u = WfH[((ks<<3)+nt0)*64 + lane];
      wl.u = WfL[((ks<<3)+nt0)*64 + lane];
      sacc0 = mfma16(vh, wh, sacc0);
      sacc0 = mfma16(vh, wl, sacc0);
      sacc0 = mfma16(vl, wh, sacc0);
      wh.u = WfH[((ks<<3)+nt0+1)*64 + lane];
      wl.u = WfL[((ks<<3)+nt0+1)*64 + lane];
      sacc1 = mfma16(vh, wh, sacc1);
      sacc1 = mfma16(vh, wl, sacc1);
      sacc1 = mfma16(vl, wh, sacc1);
    }
    if (quad == 0){
      int col0 = c + (w<<5);
      lds_s1[col0]      = sacc0[0] + bf1[col0];
      lds_s1[col0 + 16] = sacc1[0] + bf1[col0 + 16];
    }
  }
  __syncthreads();  // [Bh3] s1 ready

  // P = h @ Wa (3-pass split), epilogue: out_n = sum_j relu(P+s1)[j]*Wf2[j]
  const uint4v* WaH = (const uint4v*)(ws + WS_WA_H);
  const uint4v* WaL = (const uint4v*)(ws + WS_WA_L);
  float outacc[4] = {0.f,0.f,0.f,0.f};
  for (int nt = 0; nt < 8; ++nt){
    f32x4 g = {0.f,0.f,0.f,0.f};
    for (int ks = 0; ks < 2; ++ks){
      U4 wh, wl;
      wh.u = WaH[((ks<<3)+nt)*64 + lane];
      wl.u = WaL[((ks<<3)+nt)*64 + lane];
      g = mfma16(hh[ks], wh, g);
      g = mfma16(hh[ks], wl, g);
      g = mfma16(hl[ks], wh, g);
    }
    int col = c + (nt<<4);
    float sv = lds_s1[col];
    float w2 = Wf2[col];
    for (int r = 0; r < 4; ++r){
      float zz = fmaxf(g[r] + sv, 0.f);
      outacc[r] += zz * w2;
    }
  }
  {
    float bb = bf2[0];
    for (int r = 0; r < 4; ++r){
      float v = outacc[r];
      v += __shfl_xor(v, 1); v += __shfl_xor(v, 2);
      v += __shfl_xor(v, 4); v += __shfl_xor(v, 8);
      if (c == 0){
        int row = (w<<4) + (quad<<2) + r;
        if (row < 63) out[item*63 + row] = v + bb;
      }
    }
  }
}

extern "C" void kernel_launch(void* const* d_in, const int* in_sizes, int n_in,
                              void* d_out, int out_size, void* d_ws, size_t ws_size,
                              hipStream_t stream)
{
  const float* dobs = (const float*)d_in[0];
  const float* sobs = (const float*)d_in[1];
  const float* adj  = (const float*)d_in[2];
  const float* Wdev = (const float*)d_in[3];
  const float* bdev = (const float*)d_in[4];
  const float* Wsrv = (const float*)d_in[5];
  const float* bsrv = (const float*)d_in[6];
  const float* W1   = (const float*)d_in[7];
  const float* b1   = (const float*)d_in[8];
  const float* W2   = (const float*)d_in[9];
  const float* b2   = (const float*)d_in[10];
  const float* W3   = (const float*)d_in[11];
  const float* b3   = (const float*)d_in[12];
  const float* Wf1  = (const float*)d_in[13];
  const float* bf1  = (const float*)d_in[14];
  const float* Wf2  = (const float*)d_in[15];
  const float* bf2  = (const float*)d_in[16];
  float* out = (float*)d_out;
  char* ws = (char*)d_ws;
  int nb = in_sizes[1] / 3;   // batch size (server_obs is B x 3)

  prep_weights<<<dim3(160), dim3(256), 0, stream>>>(Wdev, W1, W2, W3, Wf1, ws);
  pgcn_fused<<<dim3(nb), dim3(256), 0, stream>>>(dobs, sobs, adj, bdev, Wsrv, bsrv,
                                                 b1, b2, b3, bf1, Wf2, bf2, ws, out);
}